// Round 2
// baseline (1132.597 us; speedup 1.0000x reference)
//
#include <hip/hip_runtime.h>
#include <hip/hip_bf16.h>
#include <type_traits>

typedef __attribute__((ext_vector_type(8))) short short8;
typedef __attribute__((ext_vector_type(4))) float f32x4;
using bf16 = __hip_bfloat16;

#define T_SEQ 2048
#define NH 32
#define SCALE_F 0.07216878364870323f   // 192^-0.5

__device__ inline unsigned short f2bf(float f) {
    unsigned u = __builtin_bit_cast(unsigned, f);
    return (unsigned short)((u + 0x7fffu + ((u >> 16) & 1u)) >> 16);
}

__device__ inline short8 ld8(const bf16* p) { return *(const short8*)p; }
__device__ inline short8 ld8(const float* p) {
    f32x4 a = *(const f32x4*)p, b = *(const f32x4*)(p + 4);
    short8 r;
    r[0] = (short)f2bf(a[0]); r[1] = (short)f2bf(a[1]);
    r[2] = (short)f2bf(a[2]); r[3] = (short)f2bf(a[3]);
    r[4] = (short)f2bf(b[0]); r[5] = (short)f2bf(b[1]);
    r[6] = (short)f2bf(b[2]); r[7] = (short)f2bf(b[3]);
    return r;
}

// ---------------------------------------------------------------------------
// GEMM: C[M,N] = A[M,K] * op(B).  BT=1: B is [N,K] row-major ("NT").
// BT=0: B is [K,N] row-major ("NN", transposed on LDS write).
// TA/TB in {float,bf16} (converted to bf16 during LDS staging), TC in
// {float,bf16}. 64x64 tile, BK=32, 4 waves, each wave a 32x32 quadrant
// (2x2 frags of mfma_f32_16x16x32_bf16). fp32 accum.
// ---------------------------------------------------------------------------
template <int BT, typename TA, typename TB, typename TC>
__global__ __launch_bounds__(256) void gemm_kernel(
    const TA* __restrict__ A, const TB* __restrict__ B, TC* __restrict__ C,
    int K, int lda, int ldb, int ldc,
    long aStride, long bStride, long cStride)
{
    const int z = blockIdx.z;
    A += (long)z * aStride; B += (long)z * bStride; C += (long)z * cStride;
    const int bm = blockIdx.y * 64, bn = blockIdx.x * 64;
    __shared__ __align__(16) short As[64][40];
    __shared__ __align__(16) short Bs[64][40];
    const int tid = threadIdx.x;
    const int lane = tid & 63;
    const int w = tid >> 6;
    const int wr = (w >> 1) * 32, wc = (w & 1) * 32;
    const int l15 = lane & 15, lg = lane >> 4;
    f32x4 acc[2][2] = {};
    for (int k0 = 0; k0 < K; k0 += 32) {
        {   // stage A: 64 rows x 32 k; thread -> row tid>>2, 8-elem chunk tid&3
            const int r = tid >> 2, cch = (tid & 3) * 8;
            *(short8*)&As[r][cch] = ld8(A + (long)(bm + r) * lda + k0 + cch);
            if (BT) {
                *(short8*)&Bs[r][cch] = ld8(B + (long)(bn + r) * ldb + k0 + cch);
            } else {
                const int kr = tid >> 3, nch = (tid & 7) * 8;
                short8 v = ld8(B + (long)(k0 + kr) * ldb + bn + nch);
                #pragma unroll
                for (int j = 0; j < 8; ++j) Bs[nch + j][kr] = v[j];
            }
        }
        __syncthreads();
        short8 af[2], bfb[2];
        #pragma unroll
        for (int i = 0; i < 2; ++i) {
            af[i]  = *(const short8*)&As[wr + i * 16 + l15][lg * 8];
            bfb[i] = *(const short8*)&Bs[wc + i * 16 + l15][lg * 8];
        }
        #pragma unroll
        for (int mi = 0; mi < 2; ++mi)
            #pragma unroll
            for (int ni = 0; ni < 2; ++ni)
                acc[mi][ni] = __builtin_amdgcn_mfma_f32_16x16x32_bf16(
                    af[mi], bfb[ni], acc[mi][ni], 0, 0, 0);
        __syncthreads();
    }
    // C/D layout: row = (lane>>4)*4 + i, col = lane&15
    #pragma unroll
    for (int mi = 0; mi < 2; ++mi)
        #pragma unroll
        for (int ni = 0; ni < 2; ++ni)
            #pragma unroll
            for (int i = 0; i < 4; ++i) {
                int row = bm + wr + mi * 16 + lg * 4 + i;
                int col = bn + wc + ni * 16 + l15;
                if constexpr (std::is_same<TC, float>::value)
                    C[(long)row * ldc + col] = acc[mi][ni][i];
                else
                    ((unsigned short*)C)[(long)row * ldc + col] = f2bf(acc[mi][ni][i]);
            }
}

// ---------------------------------------------------------------------------
// In-place RMSNorm over rows of bf16 x, fp32 weight.
// ---------------------------------------------------------------------------
__global__ __launch_bounds__(256) void rmsnorm_kernel(
    bf16* __restrict__ x, const float* __restrict__ w, int C, int ld)
{
    bf16* row = x + (long)blockIdx.x * ld;
    float ss = 0.f;
    for (int i = threadIdx.x; i < C; i += 256) {
        float v = __bfloat162float(row[i]);
        ss += v * v;
    }
    #pragma unroll
    for (int m = 1; m < 64; m <<= 1) ss += __shfl_xor(ss, m, 64);
    __shared__ float red[4];
    if ((threadIdx.x & 63) == 0) red[threadIdx.x >> 6] = ss;
    __syncthreads();
    ss = red[0] + red[1] + red[2] + red[3];
    float scale = rsqrtf(ss / (float)C + 1e-6f);
    for (int i = threadIdx.x; i < C; i += 256) {
        float v = __bfloat162float(row[i]);
        row[i] = __float2bfloat16(v * scale * w[i]);
    }
}

// ---------------------------------------------------------------------------
// In-place rope+scale on q: q[t][h][0:128] *= SCALE; [128:192] roped*SCALE
// ---------------------------------------------------------------------------
__global__ __launch_bounds__(128) void ropeq_kernel(bf16* __restrict__ q)
{
    const int t = blockIdx.x, h = blockIdx.y, i = threadIdx.x;
    bf16* base = q + ((long)t * NH + h) * 192;
    float v = __bfloat162float(base[i]) * SCALE_F;
    if (i < 32) {
        float x1 = __bfloat162float(base[128 + i]);
        float x2 = __bfloat162float(base[160 + i]);
        float inv = powf(10000.f, -(float)i / 32.f);
        float ang = (float)t * inv, s, c;
        sincosf(ang, &s, &c);
        base[128 + i] = __float2bfloat16((x1 * c - x2 * s) * SCALE_F);
        base[160 + i] = __float2bfloat16((x2 * c + x1 * s) * SCALE_F);
    }
    base[i] = __float2bfloat16(v);
}

// ---------------------------------------------------------------------------
// rope k_pe from ckv_full[:,512:576] (bf16), broadcast into kf[h][t][128:192]
// ---------------------------------------------------------------------------
__global__ __launch_bounds__(64) void ropek_kernel(
    const bf16* __restrict__ ckv, bf16* __restrict__ kf)
{
    const int t = blockIdx.x, i = threadIdx.x;
    if (i >= 32) return;
    float x1 = __bfloat162float(ckv[(long)t * 576 + 512 + i]);
    float x2 = __bfloat162float(ckv[(long)t * 576 + 544 + i]);
    float inv = powf(10000.f, -(float)i / 32.f);
    float ang = (float)t * inv, s, c;
    sincosf(ang, &s, &c);
    bf16 o1 = __float2bfloat16(x1 * c - x2 * s);
    bf16 o2 = __float2bfloat16(x2 * c + x1 * s);
    for (int h = 0; h < NH; ++h) {
        bf16* kb = kf + ((long)h * T_SEQ + t) * 192;
        kb[128 + i] = o1;
        kb[160 + i] = o2;
    }
}

// ---------------------------------------------------------------------------
// Flash attention, causal, d=192, dv=128. Block = 4 waves x 16 q-rows.
// S^T = mfma(K,Q) so softmax state is lane-local (q = lane&15); P^T
// redistribution to PV B-operand = 8 shfl of packed bf16 pairs. O kept
// transposed in 8 f32x4 frags.
// ---------------------------------------------------------------------------
__global__ __launch_bounds__(256) void attn_kernel(
    const bf16* __restrict__ Q,   // [T][H][192] scaled+roped
    const bf16* __restrict__ Kf,  // [H][T][192]
    const bf16* __restrict__ Vf,  // [H][T][128]
    bf16* __restrict__ O)         // [T][H*128]
{
    const int h = blockIdx.y;
    const int q0 = blockIdx.x * 64;
    const int tid = threadIdx.x, lane = tid & 63, w = tid >> 6;
    const int l15 = lane & 15, lg = lane >> 4;
    const int qw = q0 + w * 16;
    __shared__ __align__(16) short Ks[32][200];   // [kv][d], 16B-aligned rows
    __shared__ __align__(16) short Vs[128][40];   // [dv][kv]

    short8 qf[6];
    {
        const bf16* qp = Q + (long)(qw + l15) * (NH * 192) + (long)h * 192;
        #pragma unroll
        for (int c = 0; c < 6; ++c) qf[c] = *(const short8*)(qp + c * 32 + lg * 8);
    }
    f32x4 oacc[8] = {};
    float m = -INFINITY, lsum = 0.f;   // state for q = qw + l15 (replicated over lg)

    const int kv_end = q0 + 64;
    for (int s0 = 0; s0 < kv_end; s0 += 32) {
        {   // stage K tile [32][192]
            const int r = tid >> 3, cb2 = (tid & 7) * 24;
            const bf16* kp = Kf + ((long)h * T_SEQ + s0 + r) * 192 + cb2;
            *(short8*)&Ks[r][cb2]      = *(const short8*)kp;
            *(short8*)&Ks[r][cb2 + 8]  = *(const short8*)(kp + 8);
            *(short8*)&Ks[r][cb2 + 16] = *(const short8*)(kp + 16);
            // stage V transposed -> Vs[dv][kv]
            const int dch = (tid & 7) * 16;
            const bf16* vp = Vf + ((long)h * T_SEQ + s0 + r) * 128 + dch;
            short8 v0 = *(const short8*)vp, v1 = *(const short8*)(vp + 8);
            #pragma unroll
            for (int j = 0; j < 8; ++j) { Vs[dch + j][r] = v0[j]; Vs[dch + 8 + j][r] = v1[j]; }
        }
        __syncthreads();
        if (s0 <= qw + 15) {
            f32x4 st[2] = {};
            #pragma unroll
            for (int cb = 0; cb < 2; ++cb)
                #pragma unroll
                for (int c = 0; c < 6; ++c) {
                    short8 kfr = *(const short8*)&Ks[cb * 16 + l15][c * 32 + lg * 8];
                    st[cb] = __builtin_amdgcn_mfma_f32_16x16x32_bf16(kfr, qf[c], st[cb], 0, 0, 0);
                }
            // mask + row stats (S^T: row kv = cb*16 + lg*4 + i, col q = l15)
            const int qg = qw + l15;
            float pmax = -INFINITY;
            #pragma unroll
            for (int cb = 0; cb < 2; ++cb)
                #pragma unroll
                for (int i = 0; i < 4; ++i) {
                    int kv = s0 + cb * 16 + lg * 4 + i;
                    float v = (kv <= qg) ? st[cb][i] : -INFINITY;
                    st[cb][i] = v;
                    pmax = fmaxf(pmax, v);
                }
            pmax = fmaxf(pmax, __shfl_xor(pmax, 16, 64));
            pmax = fmaxf(pmax, __shfl_xor(pmax, 32, 64));
            float newm = fmaxf(m, pmax);
            float mm = (newm == -INFINITY) ? 0.f : newm;
            float alpha = __expf(m - mm);
            float p[2][4];
            float ps = 0.f;
            #pragma unroll
            for (int cb = 0; cb < 2; ++cb)
                #pragma unroll
                for (int i = 0; i < 4; ++i) {
                    float e = __expf(st[cb][i] - mm);
                    p[cb][i] = e; ps += e;
                }
            ps += __shfl_xor(ps, 16, 64);
            ps += __shfl_xor(ps, 32, 64);
            lsum = lsum * alpha + ps;
            m = newm;
            #pragma unroll
            for (int mb = 0; mb < 8; ++mb) oacc[mb] *= alpha;
            // P^T -> PV B-operand frag: pb[j] = P[q=l15][kv = 8*lg + j]
            unsigned pk[4];
            #pragma unroll
            for (int i = 0; i < 4; ++i)
                pk[i] = (unsigned)f2bf(p[0][i]) | ((unsigned)f2bf(p[1][i]) << 16);
            short8 pb;
            #pragma unroll
            for (int j = 0; j < 8; ++j) {
                int src = l15 + (((2 * lg + (j >> 2)) & 3) << 4);
                unsigned u = (unsigned)__shfl((int)pk[j & 3], src, 64);
                pb[j] = (short)((lg >> 1) ? (u >> 16) : (u & 0xffffu));
            }
            // PV: O^T[dv][q] += V^T * P^T
            #pragma unroll
            for (int mb = 0; mb < 8; ++mb) {
                short8 vfr = *(const short8*)&Vs[mb * 16 + l15][lg * 8];
                oacc[mb] = __builtin_amdgcn_mfma_f32_16x16x32_bf16(vfr, pb, oacc[mb], 0, 0, 0);
            }
        }
        __syncthreads();
    }
    const float inv = 1.f / lsum;
    const int qg = qw + l15;
    #pragma unroll
    for (int mb = 0; mb < 8; ++mb)
        #pragma unroll
        for (int i = 0; i < 4; ++i) {
            int dv = mb * 16 + lg * 4 + i;
            O[(long)qg * (NH * 128) + h * 128 + dv] = __float2bfloat16(oacc[mb][i] * inv);
        }
}

// ---------------------------------------------------------------------------
extern "C" void kernel_launch(void* const* d_in, const int* in_sizes, int n_in,
                              void* d_out, int out_size, void* d_ws, size_t ws_size,
                              hipStream_t stream)
{
    const float* hidden    = (const float*)d_in[0];
    // d_in[1] = position_ids (always arange(T); row index used instead)
    const float* w_q_a     = (const float*)d_in[2];
    const float* q_a_ln_w  = (const float*)d_in[3];
    const float* w_q_b     = (const float*)d_in[4];
    const float* w_kv_a    = (const float*)d_in[5];
    const float* kv_a_ln_w = (const float*)d_in[6];
    const float* w_kc      = (const float*)d_in[7];
    const float* w_vc      = (const float*)d_in[8];
    const float* w_o       = (const float*)d_in[9];
    float* out = (float*)d_out;

    bf16* qa  = (bf16*)d_ws;                  // [2048][1536]
    bf16* q   = qa  + (long)T_SEQ * 1536;     // [2048][32][192]
    bf16* ckv = q   + (long)T_SEQ * 6144;     // [2048][576]
    bf16* kf  = ckv + (long)T_SEQ * 576;      // [32][2048][192]
    bf16* vf  = kf  + (long)NH * T_SEQ * 192; // [32][2048][128]
    bf16* ov  = vf  + (long)NH * T_SEQ * 128; // [2048][4096]

    // 1. qa = hidden @ w_q_a^T          (M=2048,N=1536,K=5120)
    gemm_kernel<1, float, float, bf16><<<dim3(1536 / 64, T_SEQ / 64, 1), 256, 0, stream>>>(
        hidden, w_q_a, qa, 5120, 5120, 5120, 1536, 0, 0, 0);
    // 2. rmsnorm(qa) in place
    rmsnorm_kernel<<<dim3(T_SEQ), 256, 0, stream>>>(qa, q_a_ln_w, 1536, 1536);
    // 3. q = qa @ w_q_b^T               (M=2048,N=6144,K=1536)
    gemm_kernel<1, bf16, float, bf16><<<dim3(6144 / 64, T_SEQ / 64, 1), 256, 0, stream>>>(
        qa, w_q_b, q, 1536, 1536, 1536, 6144, 0, 0, 0);
    // 4. rope+scale q in place
    ropeq_kernel<<<dim3(T_SEQ, NH), 128, 0, stream>>>(q);
    // 5. ckv = hidden @ w_kv_a^T        (M=2048,N=576,K=5120)
    gemm_kernel<1, float, float, bf16><<<dim3(576 / 64, T_SEQ / 64, 1), 256, 0, stream>>>(
        hidden, w_kv_a, ckv, 5120, 5120, 5120, 576, 0, 0, 0);
    // 6. rmsnorm(ckv[:, :512]) in place
    rmsnorm_kernel<<<dim3(T_SEQ), 256, 0, stream>>>(ckv, kv_a_ln_w, 512, 576);
    // 7. rope k_pe -> kf[h][t][128:192]
    ropek_kernel<<<dim3(T_SEQ), 64, 0, stream>>>(ckv, kf);
    // 8. k_nope[h] = ckv_n @ w_kc[h]^T  (batched NT, M=2048,N=128,K=512)
    gemm_kernel<1, bf16, float, bf16><<<dim3(2, T_SEQ / 64, NH), 256, 0, stream>>>(
        ckv, w_kc, kf, 512, 576, 512, 192,
        0, (long)128 * 512, (long)T_SEQ * 192);
    // 9. v[h] = ckv_n @ w_vc[h]         (batched NN, M=2048,N=128,K=512)
    gemm_kernel<0, bf16, float, bf16><<<dim3(2, T_SEQ / 64, NH), 256, 0, stream>>>(
        ckv, w_vc, vf, 512, 576, 128, 128,
        0, (long)512 * 128, (long)T_SEQ * 128);
    // 10. attention
    attn_kernel<<<dim3(T_SEQ / 64, NH), 256, 0, stream>>>(q, kf, vf, ov);
    // 11. out = ov @ w_o^T              (M=2048,N=5120,K=4096), fp32 out
    gemm_kernel<1, bf16, float, float><<<dim3(5120 / 64, T_SEQ / 64, 1), 256, 0, stream>>>(
        ov, w_o, out, 4096, 4096, 4096, 5120, 0, 0, 0);
}

// Round 3
// 733.355 us; speedup vs baseline: 1.5444x; 1.5444x over previous
//
#include <hip/hip_runtime.h>
#include <hip/hip_bf16.h>
#include <type_traits>

typedef __attribute__((ext_vector_type(8))) short short8;
typedef __attribute__((ext_vector_type(4))) float f32x4;
using bf16 = __hip_bfloat16;

#define T_SEQ 2048
#define NH 32
#define SCALE_F 0.07216878364870323f   // 192^-0.5

__device__ inline unsigned short f2bf(float f) {
    unsigned u = __builtin_bit_cast(unsigned, f);
    return (unsigned short)((u + 0x7fffu + ((u >> 16) & 1u)) >> 16);
}

__device__ inline short8 ld8(const bf16* p) { return *(const short8*)p; }
__device__ inline short8 ld8(const float* p) {
    f32x4 a = *(const f32x4*)p, b = *(const f32x4*)(p + 4);
    short8 r;
    r[0] = (short)f2bf(a[0]); r[1] = (short)f2bf(a[1]);
    r[2] = (short)f2bf(a[2]); r[3] = (short)f2bf(a[3]);
    r[4] = (short)f2bf(b[0]); r[5] = (short)f2bf(b[1]);
    r[6] = (short)f2bf(b[2]); r[7] = (short)f2bf(b[3]);
    return r;
}

__device__ inline void gload_lds16(const void* g, void* l) {
    __builtin_amdgcn_global_load_lds(
        (const __attribute__((address_space(1))) unsigned*)g,
        (__attribute__((address_space(3))) unsigned*)l, 16, 0, 0);
}

// ---------------------------------------------------------------------------
// Fast GEMM (m97 structure): C[M,N] = A[M,K] * B^T, A/B bf16 row-major
// ([M,K] / [N,K]). 128x128 tile, BK=32, 4 waves each owning a 64x64 quadrant
// (4x4 frags of mfma_f32_16x16x32_bf16). global_load_lds width-16 staging
// into linear LDS. Requires M%128==0, N%128==0, K%32==0, lda/ldb %8==0.
// ---------------------------------------------------------------------------
template <typename TC>
__global__ __launch_bounds__(256) void gemm128_kernel(
    const bf16* __restrict__ A, const bf16* __restrict__ B, TC* __restrict__ C,
    int K, int lda, int ldb, int ldc,
    long aStride, long bStride, long cStride)
{
    const int z = blockIdx.z;
    A += (long)z * aStride; B += (long)z * bStride; C += (long)z * cStride;
    const int bm = blockIdx.y * 128, bn = blockIdx.x * 128;
    __shared__ __align__(16) short As[128][32];
    __shared__ __align__(16) short Bs[128][32];
    const int tid = threadIdx.x, lane = tid & 63, w = tid >> 6;
    const int l15 = lane & 15, lg = lane >> 4;
    const int wr = (w >> 1) * 64, wc = (w & 1) * 64;
    const int lrow = lane >> 2, lch = (lane & 3) * 8;   // gload lane mapping
    f32x4 acc[4][4] = {};
    for (int k0 = 0; k0 < K; k0 += 32) {
        #pragma unroll
        for (int j = 0; j < 2; ++j) {
            const int p = w * 2 + j;                    // 16-row panel 0..7
            gload_lds16(A + (long)(bm + p * 16 + lrow) * lda + k0 + lch, &As[p * 16][0]);
            gload_lds16(B + (long)(bn + p * 16 + lrow) * ldb + k0 + lch, &Bs[p * 16][0]);
        }
        __syncthreads();
        short8 af[4], bfr[4];
        #pragma unroll
        for (int i = 0; i < 4; ++i) {
            af[i]  = *(const short8*)&As[wr + i * 16 + l15][lg * 8];
            bfr[i] = *(const short8*)&Bs[wc + i * 16 + l15][lg * 8];
        }
        #pragma unroll
        for (int mi = 0; mi < 4; ++mi)
            #pragma unroll
            for (int ni = 0; ni < 4; ++ni)
                acc[mi][ni] = __builtin_amdgcn_mfma_f32_16x16x32_bf16(
                    af[mi], bfr[ni], acc[mi][ni], 0, 0, 0);
        __syncthreads();
    }
    #pragma unroll
    for (int mi = 0; mi < 4; ++mi)
        #pragma unroll
        for (int ni = 0; ni < 4; ++ni)
            #pragma unroll
            for (int i = 0; i < 4; ++i) {
                const int row = bm + wr + mi * 16 + lg * 4 + i;
                const int col = bn + wc + ni * 16 + l15;
                if constexpr (std::is_same<TC, float>::value)
                    C[(long)row * ldc + col] = acc[mi][ni][i];
                else
                    ((unsigned short*)C)[(long)row * ldc + col] = f2bf(acc[mi][ni][i]);
            }
}

// ---------------------------------------------------------------------------
// Small GEMM (64x64 tile) for odd shapes (N=576). BT=1: B is [N,K].
// ---------------------------------------------------------------------------
template <int BT, typename TA, typename TB, typename TC>
__global__ __launch_bounds__(256) void gemm_kernel(
    const TA* __restrict__ A, const TB* __restrict__ B, TC* __restrict__ C,
    int K, int lda, int ldb, int ldc,
    long aStride, long bStride, long cStride)
{
    const int z = blockIdx.z;
    A += (long)z * aStride; B += (long)z * bStride; C += (long)z * cStride;
    const int bm = blockIdx.y * 64, bn = blockIdx.x * 64;
    __shared__ __align__(16) short As[64][40];
    __shared__ __align__(16) short Bs[64][40];
    const int tid = threadIdx.x;
    const int lane = tid & 63;
    const int w = tid >> 6;
    const int wr = (w >> 1) * 32, wc = (w & 1) * 32;
    const int l15 = lane & 15, lg = lane >> 4;
    f32x4 acc[2][2] = {};
    for (int k0 = 0; k0 < K; k0 += 32) {
        {
            const int r = tid >> 2, cch = (tid & 3) * 8;
            *(short8*)&As[r][cch] = ld8(A + (long)(bm + r) * lda + k0 + cch);
            if (BT) {
                *(short8*)&Bs[r][cch] = ld8(B + (long)(bn + r) * ldb + k0 + cch);
            } else {
                const int kr = tid >> 3, nch = (tid & 7) * 8;
                short8 v = ld8(B + (long)(k0 + kr) * ldb + bn + nch);
                #pragma unroll
                for (int j = 0; j < 8; ++j) Bs[nch + j][kr] = v[j];
            }
        }
        __syncthreads();
        short8 af[2], bfb[2];
        #pragma unroll
        for (int i = 0; i < 2; ++i) {
            af[i]  = *(const short8*)&As[wr + i * 16 + l15][lg * 8];
            bfb[i] = *(const short8*)&Bs[wc + i * 16 + l15][lg * 8];
        }
        #pragma unroll
        for (int mi = 0; mi < 2; ++mi)
            #pragma unroll
            for (int ni = 0; ni < 2; ++ni)
                acc[mi][ni] = __builtin_amdgcn_mfma_f32_16x16x32_bf16(
                    af[mi], bfb[ni], acc[mi][ni], 0, 0, 0);
        __syncthreads();
    }
    #pragma unroll
    for (int mi = 0; mi < 2; ++mi)
        #pragma unroll
        for (int ni = 0; ni < 2; ++ni)
            #pragma unroll
            for (int i = 0; i < 4; ++i) {
                const int row = bm + wr + mi * 16 + lg * 4 + i;
                const int col = bn + wc + ni * 16 + l15;
                if constexpr (std::is_same<TC, float>::value)
                    C[(long)row * ldc + col] = acc[mi][ni][i];
                else
                    ((unsigned short*)C)[(long)row * ldc + col] = f2bf(acc[mi][ni][i]);
            }
}

// ---------------------------------------------------------------------------
// fp32 -> bf16 bulk convert (n % 2048 == 0 in all uses)
// ---------------------------------------------------------------------------
__global__ __launch_bounds__(256) void cvt_kernel(
    const float* __restrict__ in, bf16* __restrict__ out, long n)
{
    const long i = ((long)blockIdx.x * 256 + threadIdx.x) * 8;
    if (i >= n) return;
    f32x4 a = *(const f32x4*)(in + i), b = *(const f32x4*)(in + i + 4);
    short8 r;
    r[0] = (short)f2bf(a[0]); r[1] = (short)f2bf(a[1]);
    r[2] = (short)f2bf(a[2]); r[3] = (short)f2bf(a[3]);
    r[4] = (short)f2bf(b[0]); r[5] = (short)f2bf(b[1]);
    r[6] = (short)f2bf(b[2]); r[7] = (short)f2bf(b[3]);
    *(short8*)(out + i) = r;
}

// ---------------------------------------------------------------------------
// w_vc [32][512][128] fp32  ->  w_vc^T [32][128][512] bf16 (LDS tile transpose)
// ---------------------------------------------------------------------------
__global__ __launch_bounds__(256) void tconv_kernel(
    const float* __restrict__ in, bf16* __restrict__ out)
{
    const int h = blockIdx.z, k0 = blockIdx.x * 32, d0 = blockIdx.y * 32;
    __shared__ float t[32][33];
    const int r = threadIdx.x >> 5, c = threadIdx.x & 31;   // 8 rows, 32 cols
    const float* ip = in + ((long)h * 512 + k0) * 128 + d0;
    #pragma unroll
    for (int it = 0; it < 4; ++it)
        t[r + 8 * it][c] = ip[(long)(r + 8 * it) * 128 + c];
    __syncthreads();
    bf16* op = out + ((long)h * 128 + d0) * 512 + k0;
    #pragma unroll
    for (int it = 0; it < 4; ++it)
        op[(long)(r + 8 * it) * 512 + c] = __float2bfloat16(t[c][r + 8 * it]);
}

// ---------------------------------------------------------------------------
// In-place RMSNorm over rows of bf16 x, fp32 weight.
// ---------------------------------------------------------------------------
__global__ __launch_bounds__(256) void rmsnorm_kernel(
    bf16* __restrict__ x, const float* __restrict__ w, int C, int ld)
{
    bf16* row = x + (long)blockIdx.x * ld;
    float ss = 0.f;
    for (int i = threadIdx.x; i < C; i += 256) {
        float v = __bfloat162float(row[i]);
        ss += v * v;
    }
    #pragma unroll
    for (int m = 1; m < 64; m <<= 1) ss += __shfl_xor(ss, m, 64);
    __shared__ float red[4];
    if ((threadIdx.x & 63) == 0) red[threadIdx.x >> 6] = ss;
    __syncthreads();
    ss = red[0] + red[1] + red[2] + red[3];
    float scale = rsqrtf(ss / (float)C + 1e-6f);
    for (int i = threadIdx.x; i < C; i += 256) {
        float v = __bfloat162float(row[i]);
        row[i] = __float2bfloat16(v * scale * w[i]);
    }
}

// ---------------------------------------------------------------------------
// In-place rope+scale on q
// ---------------------------------------------------------------------------
__global__ __launch_bounds__(128) void ropeq_kernel(bf16* __restrict__ q)
{
    const int t = blockIdx.x, h = blockIdx.y, i = threadIdx.x;
    bf16* base = q + ((long)t * NH + h) * 192;
    float v = __bfloat162float(base[i]) * SCALE_F;
    if (i < 32) {
        float x1 = __bfloat162float(base[128 + i]);
        float x2 = __bfloat162float(base[160 + i]);
        float inv = powf(10000.f, -(float)i / 32.f);
        float ang = (float)t * inv, s, c;
        sincosf(ang, &s, &c);
        base[128 + i] = __float2bfloat16((x1 * c - x2 * s) * SCALE_F);
        base[160 + i] = __float2bfloat16((x2 * c + x1 * s) * SCALE_F);
    }
    base[i] = __float2bfloat16(v);
}

// ---------------------------------------------------------------------------
// rope k_pe from ckv_full[:,512:576] (bf16), broadcast into kf[h][t][128:192]
// ---------------------------------------------------------------------------
__global__ __launch_bounds__(64) void ropek_kernel(
    const bf16* __restrict__ ckv, bf16* __restrict__ kf)
{
    const int t = blockIdx.x, i = threadIdx.x;
    if (i >= 32) return;
    float x1 = __bfloat162float(ckv[(long)t * 576 + 512 + i]);
    float x2 = __bfloat162float(ckv[(long)t * 576 + 544 + i]);
    float inv = powf(10000.f, -(float)i / 32.f);
    float ang = (float)t * inv, s, c;
    sincosf(ang, &s, &c);
    bf16 o1 = __float2bfloat16(x1 * c - x2 * s);
    bf16 o2 = __float2bfloat16(x2 * c + x1 * s);
    for (int h = 0; h < NH; ++h) {
        bf16* kb = kf + ((long)h * T_SEQ + t) * 192;
        kb[128 + i] = o1;
        kb[160 + i] = o2;
    }
}

// ---------------------------------------------------------------------------
// Flash attention, causal, d=192, dv=128. 4 waves x 16 q-rows per block.
// V^T supplied from global ([h][dv][t]), staged linearly via global_load_lds
// (no transpose scatter -> no LDS write conflicts).
// ---------------------------------------------------------------------------
__global__ __launch_bounds__(256) void attn_kernel(
    const bf16* __restrict__ Q,   // [T][H][192] scaled+roped
    const bf16* __restrict__ Kf,  // [H][T][192]
    const bf16* __restrict__ Vt,  // [H][128][T]  (V^T)
    bf16* __restrict__ O)         // [T][H*128]
{
    const int h = blockIdx.y;
    const int q0 = blockIdx.x * 64;
    const int tid = threadIdx.x, lane = tid & 63, w = tid >> 6;
    const int l15 = lane & 15, lg = lane >> 4;
    const int qw = q0 + w * 16;
    __shared__ __align__(16) short Ks[32][200];   // [kv][d], padded
    __shared__ __align__(16) short Vs[128][32];   // [dv][kv], linear for gload

    short8 qf[6];
    {
        const bf16* qp = Q + (long)(qw + l15) * (NH * 192) + (long)h * 192;
        #pragma unroll
        for (int c = 0; c < 6; ++c) qf[c] = *(const short8*)(qp + c * 32 + lg * 8);
    }
    f32x4 oacc[8] = {};
    float m = -INFINITY, lsum = 0.f;   // state for q = qw + l15 (replicated over lg)

    const int kv_end = q0 + 64;
    for (int s0 = 0; s0 < kv_end; s0 += 32) {
        {   // stage K tile [32][192] (reg-staged, padded rows)
            const int r = tid >> 3, cb2 = (tid & 7) * 24;
            const bf16* kp = Kf + ((long)h * T_SEQ + s0 + r) * 192 + cb2;
            *(short8*)&Ks[r][cb2]      = *(const short8*)kp;
            *(short8*)&Ks[r][cb2 + 8]  = *(const short8*)(kp + 8);
            *(short8*)&Ks[r][cb2 + 16] = *(const short8*)(kp + 16);
            // stage V^T tile [128][32] via global_load_lds (2 calls per wave)
            #pragma unroll
            for (int j = 0; j < 2; ++j) {
                const int p = w * 2 + j;
                gload_lds16(Vt + ((long)h * 128 + p * 16 + (lane >> 2)) * T_SEQ
                               + s0 + (lane & 3) * 8,
                            &Vs[p * 16][0]);
            }
        }
        __syncthreads();
        if (s0 <= qw + 15) {
            f32x4 st[2] = {};
            #pragma unroll
            for (int cb = 0; cb < 2; ++cb)
                #pragma unroll
                for (int c = 0; c < 6; ++c) {
                    short8 kfr = *(const short8*)&Ks[cb * 16 + l15][c * 32 + lg * 8];
                    st[cb] = __builtin_amdgcn_mfma_f32_16x16x32_bf16(kfr, qf[c], st[cb], 0, 0, 0);
                }
            const int qg = qw + l15;
            float pmax = -INFINITY;
            #pragma unroll
            for (int cb = 0; cb < 2; ++cb)
                #pragma unroll
                for (int i = 0; i < 4; ++i) {
                    int kv = s0 + cb * 16 + lg * 4 + i;
                    float v = (kv <= qg) ? st[cb][i] : -INFINITY;
                    st[cb][i] = v;
                    pmax = fmaxf(pmax, v);
                }
            pmax = fmaxf(pmax, __shfl_xor(pmax, 16, 64));
            pmax = fmaxf(pmax, __shfl_xor(pmax, 32, 64));
            float newm = fmaxf(m, pmax);
            float mm = (newm == -INFINITY) ? 0.f : newm;
            float alpha = __expf(m - mm);
            float p[2][4];
            float ps = 0.f;
            #pragma unroll
            for (int cb = 0; cb < 2; ++cb)
                #pragma unroll
                for (int i = 0; i < 4; ++i) {
                    float e = __expf(st[cb][i] - mm);
                    p[cb][i] = e; ps += e;
                }
            ps += __shfl_xor(ps, 16, 64);
            ps += __shfl_xor(ps, 32, 64);
            lsum = lsum * alpha + ps;
            m = newm;
            #pragma unroll
            for (int mb = 0; mb < 8; ++mb) oacc[mb] *= alpha;
            // P^T -> PV B-operand frag: pb[j] = P[q=l15][kv = 8*lg + j]
            unsigned pk[4];
            #pragma unroll
            for (int i = 0; i < 4; ++i)
                pk[i] = (unsigned)f2bf(p[0][i]) | ((unsigned)f2bf(p[1][i]) << 16);
            short8 pb;
            #pragma unroll
            for (int j = 0; j < 8; ++j) {
                int src = l15 + (((2 * lg + (j >> 2)) & 3) << 4);
                unsigned u = (unsigned)__shfl((int)pk[j & 3], src, 64);
                pb[j] = (short)((lg >> 1) ? (u >> 16) : (u & 0xffffu));
            }
            // PV: O^T[dv][q] += V^T * P^T
            #pragma unroll
            for (int mb = 0; mb < 8; ++mb) {
                short8 vfr = *(const short8*)&Vs[mb * 16 + l15][lg * 8];
                oacc[mb] = __builtin_amdgcn_mfma_f32_16x16x32_bf16(vfr, pb, oacc[mb], 0, 0, 0);
            }
        }
        __syncthreads();
    }
    const float inv = 1.f / lsum;
    const int qg = qw + l15;
    #pragma unroll
    for (int mb = 0; mb < 8; ++mb)
        #pragma unroll
        for (int i = 0; i < 4; ++i) {
            int dv = mb * 16 + lg * 4 + i;
            O[(long)qg * (NH * 128) + h * 128 + dv] = __float2bfloat16(oacc[mb][i] * inv);
        }
}

// ---------------------------------------------------------------------------
extern "C" void kernel_launch(void* const* d_in, const int* in_sizes, int n_in,
                              void* d_out, int out_size, void* d_ws, size_t ws_size,
                              hipStream_t stream)
{
    const float* hidden    = (const float*)d_in[0];
    const float* w_q_a     = (const float*)d_in[2];
    const float* q_a_ln_w  = (const float*)d_in[3];
    const float* w_q_b     = (const float*)d_in[4];
    const float* w_kv_a    = (const float*)d_in[5];
    const float* kv_a_ln_w = (const float*)d_in[6];
    const float* w_kc      = (const float*)d_in[7];
    const float* w_vc      = (const float*)d_in[8];
    const float* w_o       = (const float*)d_in[9];
    float* out = (float*)d_out;

    // workspace layout (bf16 elements)
    bf16* qa   = (bf16*)d_ws;                    // [2048][1536]
    bf16* q    = qa   + (long)T_SEQ * 1536;      // [2048][32][192]
    bf16* ckv  = q    + (long)T_SEQ * 6144;      // [2048][576]
    bf16* kf   = ckv  + (long)T_SEQ * 576;       // [32][2048][192]
    bf16* vt   = kf   + (long)NH * T_SEQ * 192;  // [32][128][2048]  (V^T)
    bf16* ov   = vt   + (long)NH * 128 * T_SEQ;  // [2048][4096]
    bf16* hb   = ov   + (long)T_SEQ * 4096;      // [2048][5120] hidden bf16
    bf16* wqa  = hb   + (long)T_SEQ * 5120;      // [1536][5120]
    bf16* wqb  = wqa  + (long)1536 * 5120;       // [6144][1536]
    bf16* wkva = wqb  + (long)6144 * 1536;       // [576][5120]
    bf16* wkc  = wkva + (long)576 * 5120;        // [32][128][512]
    bf16* wvct = wkc  + (long)NH * 128 * 512;    // [32][128][512]  (w_vc^T)
    bf16* wo   = hb;   // alias: hb/wqa/wqb/wkva dead before w_o conversion

    // --- weight / activation conversions ---
    cvt_kernel<<<dim3(5120), 256, 0, stream>>>(hidden, hb,  (long)T_SEQ * 5120);
    cvt_kernel<<<dim3(3840), 256, 0, stream>>>(w_q_a,  wqa, (long)1536 * 5120);
    cvt_kernel<<<dim3(4608), 256, 0, stream>>>(w_q_b,  wqb, (long)6144 * 1536);
    cvt_kernel<<<dim3(1440), 256, 0, stream>>>(w_kv_a, wkva,(long)576 * 5120);
    cvt_kernel<<<dim3(1024), 256, 0, stream>>>(w_kc,   wkc, (long)NH * 128 * 512);
    tconv_kernel<<<dim3(16, 4, NH), 256, 0, stream>>>(w_vc, wvct);

    // 1. qa = hb @ wqa^T            (M=2048,N=1536,K=5120)
    gemm128_kernel<bf16><<<dim3(12, 16, 1), 256, 0, stream>>>(
        hb, wqa, qa, 5120, 5120, 5120, 1536, 0, 0, 0);
    // 2. rmsnorm(qa)
    rmsnorm_kernel<<<dim3(T_SEQ), 256, 0, stream>>>(qa, q_a_ln_w, 1536, 1536);
    // 3. q = qa @ wqb^T             (M=2048,N=6144,K=1536)
    gemm128_kernel<bf16><<<dim3(48, 16, 1), 256, 0, stream>>>(
        qa, wqb, q, 1536, 1536, 1536, 6144, 0, 0, 0);
    // 4. rope+scale q
    ropeq_kernel<<<dim3(T_SEQ, NH), 128, 0, stream>>>(q);
    // 5. ckv = hb @ wkva^T          (M=2048,N=576,K=5120) — odd N, 64^2 kernel
    gemm_kernel<1, bf16, bf16, bf16><<<dim3(9, 32, 1), 256, 0, stream>>>(
        hb, wkva, ckv, 5120, 5120, 5120, 576, 0, 0, 0);
    // 6. rmsnorm(ckv[:, :512])
    rmsnorm_kernel<<<dim3(T_SEQ), 256, 0, stream>>>(ckv, kv_a_ln_w, 512, 576);
    // 7. rope k_pe -> kf[:,:,128:192]
    ropek_kernel<<<dim3(T_SEQ), 64, 0, stream>>>(ckv, kf);
    // 8. k_nope[h] = ckv_n @ wkc[h]^T  (batched, M=2048,N=128,K=512) -> kf cols 0:128
    gemm128_kernel<bf16><<<dim3(1, 16, NH), 256, 0, stream>>>(
        ckv, wkc, kf, 512, 576, 512, 192,
        0, (long)128 * 512, (long)T_SEQ * 192);
    // 9. vt[h] = wvct[h] @ ckv_n^T  (batched, M=128,N=2048,K=512) — V^T direct
    gemm128_kernel<bf16><<<dim3(16, 1, NH), 256, 0, stream>>>(
        wvct, ckv, vt, 512, 512, 576, T_SEQ,
        (long)128 * 512, 0, (long)128 * T_SEQ);
    // 10. convert w_o (aliases dead hb/wqa/wqb/wkva region)
    cvt_kernel<<<dim3(10240), 256, 0, stream>>>(w_o, wo, (long)5120 * 4096);
    // 11. attention
    attn_kernel<<<dim3(T_SEQ / 64, NH), 256, 0, stream>>>(q, kf, vt, ov);
    // 12. out = ov @ wo^T           (M=2048,N=5120,K=4096), fp32 out
    gemm128_kernel<float><<<dim3(40, 16, 1), 256, 0, stream>>>(
        ov, wo, out, 4096, 4096, 4096, 5120, 0, 0, 0);
}

// Round 4
// 687.320 us; speedup vs baseline: 1.6478x; 1.0670x over previous
//
#include <hip/hip_runtime.h>
#include <hip/hip_bf16.h>
#include <type_traits>

typedef __attribute__((ext_vector_type(8))) short short8;
typedef __attribute__((ext_vector_type(4))) float f32x4;
using bf16 = __hip_bfloat16;

#define T_SEQ 2048
#define NH 32
#define SCALE_F 0.07216878364870323f   // 192^-0.5

__device__ inline unsigned short f2bf(float f) {
    unsigned u = __builtin_bit_cast(unsigned, f);
    return (unsigned short)((u + 0x7fffu + ((u >> 16) & 1u)) >> 16);
}

__device__ inline short8 ld8(const bf16* p) { return *(const short8*)p; }
__device__ inline short8 ld8(const float* p) {
    f32x4 a = *(const f32x4*)p, b = *(const f32x4*)(p + 4);
    short8 r;
    r[0] = (short)f2bf(a[0]); r[1] = (short)f2bf(a[1]);
    r[2] = (short)f2bf(a[2]); r[3] = (short)f2bf(a[3]);
    r[4] = (short)f2bf(b[0]); r[5] = (short)f2bf(b[1]);
    r[6] = (short)f2bf(b[2]); r[7] = (short)f2bf(b[3]);
    return r;
}

__device__ inline void gload_lds16(const void* g, void* l) {
    __builtin_amdgcn_global_load_lds(
        (const __attribute__((address_space(1))) unsigned*)g,
        (__attribute__((address_space(3))) unsigned*)l, 16, 0, 0);
}

// ---------------------------------------------------------------------------
// Fast GEMM (m97 structure): C[M,N] = A[M,K] * B^T, bf16 row-major inputs.
// 128x128 tile, BK=32, 4 waves, 4x4 frags each. global_load_lds staging.
// ---------------------------------------------------------------------------
template <typename TC>
__global__ __launch_bounds__(256) void gemm128_kernel(
    const bf16* __restrict__ A, const bf16* __restrict__ B, TC* __restrict__ C,
    int K, int lda, int ldb, int ldc,
    long aStride, long bStride, long cStride)
{
    const int z = blockIdx.z;
    A += (long)z * aStride; B += (long)z * bStride; C += (long)z * cStride;
    const int bm = blockIdx.y * 128, bn = blockIdx.x * 128;
    __shared__ __align__(16) short As[128][32];
    __shared__ __align__(16) short Bs[128][32];
    const int tid = threadIdx.x, lane = tid & 63, w = tid >> 6;
    const int l15 = lane & 15, lg = lane >> 4;
    const int wr = (w >> 1) * 64, wc = (w & 1) * 64;
    const int lrow = lane >> 2, lch = (lane & 3) * 8;
    f32x4 acc[4][4] = {};
    for (int k0 = 0; k0 < K; k0 += 32) {
        #pragma unroll
        for (int j = 0; j < 2; ++j) {
            const int p = w * 2 + j;
            gload_lds16(A + (long)(bm + p * 16 + lrow) * lda + k0 + lch, &As[p * 16][0]);
            gload_lds16(B + (long)(bn + p * 16 + lrow) * ldb + k0 + lch, &Bs[p * 16][0]);
        }
        __syncthreads();
        short8 af[4], bfr[4];
        #pragma unroll
        for (int i = 0; i < 4; ++i) {
            af[i]  = *(const short8*)&As[wr + i * 16 + l15][lg * 8];
            bfr[i] = *(const short8*)&Bs[wc + i * 16 + l15][lg * 8];
        }
        #pragma unroll
        for (int mi = 0; mi < 4; ++mi)
            #pragma unroll
            for (int ni = 0; ni < 4; ++ni)
                acc[mi][ni] = __builtin_amdgcn_mfma_f32_16x16x32_bf16(
                    af[mi], bfr[ni], acc[mi][ni], 0, 0, 0);
        __syncthreads();
    }
    #pragma unroll
    for (int mi = 0; mi < 4; ++mi)
        #pragma unroll
        for (int ni = 0; ni < 4; ++ni)
            #pragma unroll
            for (int i = 0; i < 4; ++i) {
                const int row = bm + wr + mi * 16 + lg * 4 + i;
                const int col = bn + wc + ni * 16 + l15;
                if constexpr (std::is_same<TC, float>::value)
                    C[(long)row * ldc + col] = acc[mi][ni][i];
                else
                    ((unsigned short*)C)[(long)row * ldc + col] = f2bf(acc[mi][ni][i]);
            }
}

// ---------------------------------------------------------------------------
// fp32 -> bf16 bulk convert (n % 2048 == 0 in all uses)
// ---------------------------------------------------------------------------
__global__ __launch_bounds__(256) void cvt_kernel(
    const float* __restrict__ in, bf16* __restrict__ out, long n)
{
    const long i = ((long)blockIdx.x * 256 + threadIdx.x) * 8;
    if (i >= n) return;
    f32x4 a = *(const f32x4*)(in + i), b = *(const f32x4*)(in + i + 4);
    short8 r;
    r[0] = (short)f2bf(a[0]); r[1] = (short)f2bf(a[1]);
    r[2] = (short)f2bf(a[2]); r[3] = (short)f2bf(a[3]);
    r[4] = (short)f2bf(b[0]); r[5] = (short)f2bf(b[1]);
    r[6] = (short)f2bf(b[2]); r[7] = (short)f2bf(b[3]);
    *(short8*)(out + i) = r;
}

// ---------------------------------------------------------------------------
// w_vc [32][512][128] fp32  ->  w_vc^T [32][128][512] bf16
// ---------------------------------------------------------------------------
__global__ __launch_bounds__(256) void tconv_kernel(
    const float* __restrict__ in, bf16* __restrict__ out)
{
    const int h = blockIdx.z, k0 = blockIdx.x * 32, d0 = blockIdx.y * 32;
    __shared__ float t[32][33];
    const int r = threadIdx.x >> 5, c = threadIdx.x & 31;
    const float* ip = in + ((long)h * 512 + k0) * 128 + d0;
    #pragma unroll
    for (int it = 0; it < 4; ++it)
        t[r + 8 * it][c] = ip[(long)(r + 8 * it) * 128 + c];
    __syncthreads();
    bf16* op = out + ((long)h * 128 + d0) * 512 + k0;
    #pragma unroll
    for (int it = 0; it < 4; ++it)
        op[(long)(r + 8 * it) * 512 + c] = __float2bfloat16(t[c][r + 8 * it]);
}

// ---------------------------------------------------------------------------
__global__ __launch_bounds__(256) void rmsnorm_kernel(
    bf16* __restrict__ x, const float* __restrict__ w, int C, int ld)
{
    bf16* row = x + (long)blockIdx.x * ld;
    float ss = 0.f;
    for (int i = threadIdx.x; i < C; i += 256) {
        float v = __bfloat162float(row[i]);
        ss += v * v;
    }
    #pragma unroll
    for (int m = 1; m < 64; m <<= 1) ss += __shfl_xor(ss, m, 64);
    __shared__ float red[4];
    if ((threadIdx.x & 63) == 0) red[threadIdx.x >> 6] = ss;
    __syncthreads();
    ss = red[0] + red[1] + red[2] + red[3];
    float scale = rsqrtf(ss / (float)C + 1e-6f);
    for (int i = threadIdx.x; i < C; i += 256) {
        float v = __bfloat162float(row[i]);
        row[i] = __float2bfloat16(v * scale * w[i]);
    }
}

// ---------------------------------------------------------------------------
__global__ __launch_bounds__(128) void ropeq_kernel(bf16* __restrict__ q)
{
    const int t = blockIdx.x, h = blockIdx.y, i = threadIdx.x;
    bf16* base = q + ((long)t * NH + h) * 192;
    float v = __bfloat162float(base[i]) * SCALE_F;
    if (i < 32) {
        float x1 = __bfloat162float(base[128 + i]);
        float x2 = __bfloat162float(base[160 + i]);
        float inv = powf(10000.f, -(float)i / 32.f);
        float ang = (float)t * inv, s, c;
        sincosf(ang, &s, &c);
        base[128 + i] = __float2bfloat16((x1 * c - x2 * s) * SCALE_F);
        base[160 + i] = __float2bfloat16((x2 * c + x1 * s) * SCALE_F);
    }
    base[i] = __float2bfloat16(v);
}

// ---------------------------------------------------------------------------
__global__ __launch_bounds__(64) void ropek_kernel(
    const bf16* __restrict__ ckv, bf16* __restrict__ kf)
{
    const int t = blockIdx.x, i = threadIdx.x;
    if (i >= 32) return;
    float x1 = __bfloat162float(ckv[(long)t * 640 + 512 + i]);
    float x2 = __bfloat162float(ckv[(long)t * 640 + 544 + i]);
    float inv = powf(10000.f, -(float)i / 32.f);
    float ang = (float)t * inv, s, c;
    sincosf(ang, &s, &c);
    bf16 o1 = __float2bfloat16(x1 * c - x2 * s);
    bf16 o2 = __float2bfloat16(x2 * c + x1 * s);
    for (int h = 0; h < NH; ++h) {
        bf16* kb = kf + ((long)h * T_SEQ + t) * 192;
        kb[128 + i] = o1;
        kb[160 + i] = o2;
    }
}

// ---------------------------------------------------------------------------
// Flash attention, causal, d=192, dv=128.
// Block: 4 waves, 128 q-rows (32 per wave, 2 q-frags). KVBLK=64.
// K/V staged via global_load_lds into LINEAR LDS with pre-swizzled global
// source (byte col ^= (row&7)<<4); frag reads apply the same XOR -> 2-way
// bank aliasing only. S^T = mfma(K,Q): softmax state lane-local (q=lane&15).
// ---------------------------------------------------------------------------
__global__ __launch_bounds__(256, 2) void attn_kernel(
    const bf16* __restrict__ Q,   // [T][H][192] scaled+roped
    const bf16* __restrict__ Kf,  // [H][T][192]
    const bf16* __restrict__ Vt,  // [H][128][T]  (V^T)
    bf16* __restrict__ O)         // [T][H*128]
{
    const int h = blockIdx.y;
    const int q0 = (gridDim.x - 1 - blockIdx.x) * 128;   // longest blocks first
    const int tid = threadIdx.x, lane = tid & 63, w = tid >> 6;
    const int l15 = lane & 15, lg = lane >> 4;
    const int qw = q0 + w * 32;
    __shared__ __align__(16) short Ks[64 * 192];   // linear, swizzled content
    __shared__ __align__(16) short Vs[128 * 64];

    // loop-invariant swizzled intra-tile source offsets (bytes)
    int ksoff[6];
    #pragma unroll
    for (int j = 0; j < 6; ++j) {
        int o = (w * 6 + j) * 1024 + lane * 16;
        int row = o / 384, col = o % 384;
        ksoff[j] = row * 384 + (col ^ ((row & 7) << 4));
    }
    const int vrow8 = lane >> 3;                               // 0..7
    const int vscol = ((lane & 7) * 16) ^ (vrow8 << 4);        // swizzled tile col

    // Q fragments: qf[qi][c], q = qw + qi*16 + l15, k-chunk c*32 + lg*8
    short8 qf[2][6];
    #pragma unroll
    for (int qi = 0; qi < 2; ++qi) {
        const bf16* qp = Q + (long)(qw + qi * 16 + l15) * (NH * 192) + (long)h * 192;
        #pragma unroll
        for (int c = 0; c < 6; ++c) qf[qi][c] = *(const short8*)(qp + c * 32 + lg * 8);
    }

    f32x4 oacc[2][8] = {};
    float mst[2] = {-INFINITY, -INFINITY};
    float lst[2] = {0.f, 0.f};

    const char* kbase0 = (const char*)Kf + (long)h * T_SEQ * 384;
    const char* vbase0 = (const char*)Vt + (long)h * 128 * T_SEQ * 2;
    const int swz = (l15 & 7) << 4;

    for (int s0 = 0; s0 < q0 + 128; s0 += 64) {
        {   // stage K (24 KB contiguous) + V^T (16 KB strided), swizzled source
            const char* kb = kbase0 + (long)s0 * 384;
            #pragma unroll
            for (int j = 0; j < 6; ++j)
                gload_lds16(kb + ksoff[j], (char*)Ks + (w * 6 + j) * 1024);
            const char* vb = vbase0 + (long)s0 * 2 + vscol;
            #pragma unroll
            for (int j = 0; j < 4; ++j) {
                const int c = w * 4 + j;
                gload_lds16(vb + (long)(c * 8 + vrow8) * (T_SEQ * 2),
                            (char*)Vs + c * 1024);
            }
        }
        __syncthreads();
        if (s0 <= qw + 31) {
            // ---- QK^T: S^T[kv][q] ----
            f32x4 st[2][4] = {};
            __builtin_amdgcn_s_setprio(1);
            #pragma unroll
            for (int cb = 0; cb < 4; ++cb) {
                const int krow = cb * 16 + l15;
                #pragma unroll
                for (int c = 0; c < 6; ++c) {
                    short8 kfr = *(const short8*)((const char*)Ks + krow * 384
                                                  + ((c * 64 + lg * 16) ^ swz));
                    st[0][cb] = __builtin_amdgcn_mfma_f32_16x16x32_bf16(kfr, qf[0][c], st[0][cb], 0, 0, 0);
                    st[1][cb] = __builtin_amdgcn_mfma_f32_16x16x32_bf16(kfr, qf[1][c], st[1][cb], 0, 0, 0);
                }
            }
            __builtin_amdgcn_s_setprio(0);
            // ---- online softmax (per q-frag; state lane-local) ----
            short8 pb[2][2];
            #pragma unroll
            for (int qi = 0; qi < 2; ++qi) {
                const int qg = qw + qi * 16 + l15;
                float pmax = -INFINITY;
                #pragma unroll
                for (int cb = 0; cb < 4; ++cb)
                    #pragma unroll
                    for (int i = 0; i < 4; ++i) {
                        const int kv = s0 + cb * 16 + lg * 4 + i;
                        float v = (kv <= qg) ? st[qi][cb][i] : -INFINITY;
                        st[qi][cb][i] = v;
                        pmax = fmaxf(pmax, v);
                    }
                pmax = fmaxf(pmax, __shfl_xor(pmax, 16, 64));
                pmax = fmaxf(pmax, __shfl_xor(pmax, 32, 64));
                const float newm = fmaxf(mst[qi], pmax);
                const float mm = (newm == -INFINITY) ? 0.f : newm;
                const float alpha = __expf(mst[qi] - mm);
                float ps = 0.f;
                #pragma unroll
                for (int cb = 0; cb < 4; ++cb)
                    #pragma unroll
                    for (int i = 0; i < 4; ++i) {
                        const float e = __expf(st[qi][cb][i] - mm);
                        st[qi][cb][i] = e; ps += e;
                    }
                ps += __shfl_xor(ps, 16, 64);
                ps += __shfl_xor(ps, 32, 64);
                lst[qi] = lst[qi] * alpha + ps;
                mst[qi] = newm;
                #pragma unroll
                for (int mb = 0; mb < 8; ++mb) oacc[qi][mb] *= alpha;
                // P^T -> PV B-frags: pb[qi][hh][j] = P[q][kv = hh*32 + lg*8 + j]
                #pragma unroll
                for (int hh = 0; hh < 2; ++hh) {
                    unsigned pk[4];
                    #pragma unroll
                    for (int i = 0; i < 4; ++i)
                        pk[i] = (unsigned)f2bf(st[qi][2 * hh][i])
                              | ((unsigned)f2bf(st[qi][2 * hh + 1][i]) << 16);
                    #pragma unroll
                    for (int j = 0; j < 8; ++j) {
                        const int src = l15 + (((2 * lg + (j >> 2)) & 3) << 4);
                        const unsigned u = (unsigned)__shfl((int)pk[j & 3], src, 64);
                        pb[qi][hh][j] = (short)((lg >> 1) ? (u >> 16) : (u & 0xffffu));
                    }
                }
            }
            // ---- PV: O^T[dv][q] += V^T * P^T ----
            __builtin_amdgcn_s_setprio(1);
            #pragma unroll
            for (int mb = 0; mb < 8; ++mb) {
                const int vrow = mb * 16 + l15;
                #pragma unroll
                for (int hh = 0; hh < 2; ++hh) {
                    short8 vfr = *(const short8*)((const char*)Vs + vrow * 128
                                                  + ((hh * 64 + lg * 16) ^ swz));
                    oacc[0][mb] = __builtin_amdgcn_mfma_f32_16x16x32_bf16(vfr, pb[0][hh], oacc[0][mb], 0, 0, 0);
                    oacc[1][mb] = __builtin_amdgcn_mfma_f32_16x16x32_bf16(vfr, pb[1][hh], oacc[1][mb], 0, 0, 0);
                }
            }
            __builtin_amdgcn_s_setprio(0);
        }
        __syncthreads();
    }
    #pragma unroll
    for (int qi = 0; qi < 2; ++qi) {
        const float inv = 1.f / lst[qi];
        const int qg = qw + qi * 16 + l15;
        #pragma unroll
        for (int mb = 0; mb < 8; ++mb)
            #pragma unroll
            for (int i = 0; i < 4; ++i) {
                const int dv = mb * 16 + lg * 4 + i;
                O[(long)qg * (NH * 128) + h * 128 + dv] = __float2bfloat16(oacc[qi][mb][i] * inv);
            }
    }
}

// ---------------------------------------------------------------------------
extern "C" void kernel_launch(void* const* d_in, const int* in_sizes, int n_in,
                              void* d_out, int out_size, void* d_ws, size_t ws_size,
                              hipStream_t stream)
{
    const float* hidden    = (const float*)d_in[0];
    const float* w_q_a     = (const float*)d_in[2];
    const float* q_a_ln_w  = (const float*)d_in[3];
    const float* w_q_b     = (const float*)d_in[4];
    const float* w_kv_a    = (const float*)d_in[5];
    const float* kv_a_ln_w = (const float*)d_in[6];
    const float* w_kc      = (const float*)d_in[7];
    const float* w_vc      = (const float*)d_in[8];
    const float* w_o       = (const float*)d_in[9];
    float* out = (float*)d_out;

    // workspace layout (bf16 elements)
    bf16* qa   = (bf16*)d_ws;                    // [2048][1536]
    bf16* q    = qa   + (long)T_SEQ * 1536;      // [2048][32][192]
    bf16* ckv  = q    + (long)T_SEQ * 6144;      // [2048][640] (cols 576+ zero)
    bf16* kf   = ckv  + (long)T_SEQ * 640;       // [32][2048][192]
    bf16* vt   = kf   + (long)NH * T_SEQ * 192;  // [32][128][2048]  (V^T)
    bf16* ov   = vt   + (long)NH * 128 * T_SEQ;  // [2048][4096]
    bf16* hb   = ov   + (long)T_SEQ * 4096;      // [2048][5120] hidden bf16
    bf16* wqa  = hb   + (long)T_SEQ * 5120;      // [1536][5120]
    bf16* wqb  = wqa  + (long)1536 * 5120;       // [6144][1536]
    bf16* wkva = wqb  + (long)6144 * 1536;       // [640][5120] (rows 576+ zero)
    bf16* wkc  = wkva + (long)640 * 5120;        // [32][128][512]
    bf16* wvct = wkc  + (long)NH * 128 * 512;    // [32][128][512]  (w_vc^T)
    bf16* wo   = hb;   // alias: hb/wqa/wqb/wkva dead before w_o conversion

    // --- weight / activation conversions ---
    cvt_kernel<<<dim3(5120), 256, 0, stream>>>(hidden, hb,  (long)T_SEQ * 5120);
    cvt_kernel<<<dim3(3840), 256, 0, stream>>>(w_q_a,  wqa, (long)1536 * 5120);
    cvt_kernel<<<dim3(4608), 256, 0, stream>>>(w_q_b,  wqb, (long)6144 * 1536);
    cvt_kernel<<<dim3(1440), 256, 0, stream>>>(w_kv_a, wkva,(long)576 * 5120);
    hipMemsetAsync(wkva + (long)576 * 5120, 0, (long)64 * 5120 * sizeof(bf16), stream);
    cvt_kernel<<<dim3(1024), 256, 0, stream>>>(w_kc,   wkc, (long)NH * 128 * 512);
    tconv_kernel<<<dim3(16, 4, NH), 256, 0, stream>>>(w_vc, wvct);

    // 1. qa = hb @ wqa^T            (M=2048,N=1536,K=5120)
    gemm128_kernel<bf16><<<dim3(12, 16, 1), 256, 0, stream>>>(
        hb, wqa, qa, 5120, 5120, 5120, 1536, 0, 0, 0);
    // 2. rmsnorm(qa)
    rmsnorm_kernel<<<dim3(T_SEQ), 256, 0, stream>>>(qa, q_a_ln_w, 1536, 1536);
    // 3. q = qa @ wqb^T             (M=2048,N=6144,K=1536)
    gemm128_kernel<bf16><<<dim3(48, 16, 1), 256, 0, stream>>>(
        qa, wqb, q, 1536, 1536, 1536, 6144, 0, 0, 0);
    // 4. rope+scale q
    ropeq_kernel<<<dim3(T_SEQ, NH), 128, 0, stream>>>(q);
    // 5. ckv = hb @ wkva^T          (M=2048,N=640,K=5120), padded to use gemm128
    gemm128_kernel<bf16><<<dim3(5, 16, 1), 256, 0, stream>>>(
        hb, wkva, ckv, 5120, 5120, 5120, 640, 0, 0, 0);
    // 6. rmsnorm(ckv[:, :512])
    rmsnorm_kernel<<<dim3(T_SEQ), 256, 0, stream>>>(ckv, kv_a_ln_w, 512, 640);
    // 7. rope k_pe -> kf[:,:,128:192]
    ropek_kernel<<<dim3(T_SEQ), 64, 0, stream>>>(ckv, kf);
    // 8. k_nope[h] = ckv_n @ wkc[h]^T  (batched, M=2048,N=128,K=512) -> kf cols 0:128
    gemm128_kernel<bf16><<<dim3(1, 16, NH), 256, 0, stream>>>(
        ckv, wkc, kf, 512, 640, 512, 192,
        0, (long)128 * 512, (long)T_SEQ * 192);
    // 9. vt[h] = wvct[h] @ ckv_n^T  (batched, M=128,N=2048,K=512) — V^T direct
    gemm128_kernel<bf16><<<dim3(16, 1, NH), 256, 0, stream>>>(
        wvct, ckv, vt, 512, 512, 640, T_SEQ,
        (long)128 * 512, 0, (long)128 * T_SEQ);
    // 10. convert w_o (aliases dead hb/wqa/wqb/wkva region)
    cvt_kernel<<<dim3(10240), 256, 0, stream>>>(w_o, wo, (long)5120 * 4096);
    // 11. attention (128 q-rows per block, reversed dispatch)
    attn_kernel<<<dim3(T_SEQ / 128, NH), 256, 0, stream>>>(q, kf, vt, ov);
    // 12. out = ov @ wo^T           (M=2048,N=5120,K=4096), fp32 out
    gemm128_kernel<float><<<dim3(40, 16, 1), 256, 0, stream>>>(
        ov, wo, out, 4096, 4096, 4096, 5120, 0, 0, 0);
}

// Round 5
// 655.062 us; speedup vs baseline: 1.7290x; 1.0492x over previous
//
#include <hip/hip_runtime.h>
#include <hip/hip_bf16.h>
#include <type_traits>

typedef __attribute__((ext_vector_type(8))) short short8;
typedef __attribute__((ext_vector_type(4))) float f32x4;
using bf16 = __hip_bfloat16;

#define T_SEQ 2048
#define NH 32
#define SCALE_F 0.07216878364870323f   // 192^-0.5

__device__ inline unsigned short f2bf(float f) {
    unsigned u = __builtin_bit_cast(unsigned, f);
    return (unsigned short)((u + 0x7fffu + ((u >> 16) & 1u)) >> 16);
}

__device__ inline void gload_lds16(const void* g, void* l) {
    __builtin_amdgcn_global_load_lds(
        (const __attribute__((address_space(1))) unsigned*)g,
        (__attribute__((address_space(3))) unsigned*)l, 16, 0, 0);
}

// ---------------------------------------------------------------------------
// Pipelined GEMM: C[M,N] = A[M,K] * B^T (A [M,K], B [N,K] bf16 row-major).
// BM=BN=128, BK=64, 8 waves (512 thr). Double-buffered LDS (64 KB), counted
// vmcnt(4): next tile's global_load_lds stay in flight across barriers.
// Waves: wm=w>>1 (4 M-quads), wn=w&1 (2 N-halves); per-wave 32x64 = 2x4 frags.
// Requires M%128==0, N%128==0, K%64==0, lda/ldb %8==0.
// ---------------------------------------------------------------------------
template <typename TC>
__global__ __launch_bounds__(512, 4) void gemm8w_kernel(
    const bf16* __restrict__ A, const bf16* __restrict__ B, TC* __restrict__ C,
    int K, int lda, int ldb, int ldc,
    long aStride, long bStride, long cStride)
{
    const int z = blockIdx.z;
    A += (long)z * aStride; B += (long)z * bStride; C += (long)z * cStride;
    const int bm = blockIdx.y * 128, bn = blockIdx.x * 128;
    __shared__ __align__(16) short As[2][128 * 64];
    __shared__ __align__(16) short Bs[2][128 * 64];
    const int tid = threadIdx.x, lane = tid & 63, w = tid >> 6;
    const int l15 = lane & 15, lg = lane >> 4;
    const int wm = w >> 1, wn = w & 1;
    // staging: chunk c = w*2+j covers LDS bytes [c*1024, +1024) = rows c*8..c*8+7
    const int c0 = w * 2, c1 = w * 2 + 1;
    const int srow0 = c0 * 8 + (lane >> 3), srow1 = c1 * 8 + (lane >> 3);
    const int scol = (lane & 7) * 16;   // byte col within 128B row
    const bf16* Ab = A + (long)bm * lda;
    const bf16* Bb = B + (long)bn * ldb;

    auto stage = [&](int buf, int k0) {
        const char* ag = (const char*)(Ab + k0);
        const char* bg = (const char*)(Bb + k0);
        gload_lds16(ag + (long)srow0 * (lda * 2) + scol, &As[buf][c0 * 512]);
        gload_lds16(ag + (long)srow1 * (lda * 2) + scol, &As[buf][c1 * 512]);
        gload_lds16(bg + (long)srow0 * (ldb * 2) + scol, &Bs[buf][c0 * 512]);
        gload_lds16(bg + (long)srow1 * (ldb * 2) + scol, &Bs[buf][c1 * 512]);
    };

    f32x4 acc[2][4] = {};
    const int nt = K >> 6;
    stage(0, 0);
    for (int t = 0; t < nt; ++t) {
        if (t + 1 < nt) {
            stage((t + 1) & 1, (t + 1) << 6);
            asm volatile("s_waitcnt vmcnt(4)" ::: "memory");   // this tile done; next in flight
        } else {
            asm volatile("s_waitcnt vmcnt(0)" ::: "memory");
        }
        __builtin_amdgcn_s_barrier();
        __builtin_amdgcn_sched_barrier(0);
        const char* Ap = (const char*)&As[t & 1][0];
        const char* Bp = (const char*)&Bs[t & 1][0];
        short8 af[2][2], bfv[4][2];
        #pragma unroll
        for (int fi = 0; fi < 2; ++fi)
            #pragma unroll
            for (int ks = 0; ks < 2; ++ks)
                af[fi][ks] = *(const short8*)(Ap + (wm * 32 + fi * 16 + l15) * 128 + ks * 64 + lg * 16);
        #pragma unroll
        for (int nj = 0; nj < 4; ++nj)
            #pragma unroll
            for (int ks = 0; ks < 2; ++ks)
                bfv[nj][ks] = *(const short8*)(Bp + (wn * 64 + nj * 16 + l15) * 128 + ks * 64 + lg * 16);
        #pragma unroll
        for (int ks = 0; ks < 2; ++ks)
            #pragma unroll
            for (int fi = 0; fi < 2; ++fi)
                #pragma unroll
                for (int nj = 0; nj < 4; ++nj)
                    acc[fi][nj] = __builtin_amdgcn_mfma_f32_16x16x32_bf16(
                        af[fi][ks], bfv[nj][ks], acc[fi][nj], 0, 0, 0);
        // all ds_reads must retire before freeing this buffer for overwrite
        asm volatile("s_waitcnt lgkmcnt(0)" ::: "memory");
        __builtin_amdgcn_sched_barrier(0);
        __builtin_amdgcn_s_barrier();
        __builtin_amdgcn_sched_barrier(0);
    }
    #pragma unroll
    for (int fi = 0; fi < 2; ++fi)
        #pragma unroll
        for (int nj = 0; nj < 4; ++nj)
            #pragma unroll
            for (int i = 0; i < 4; ++i) {
                const int row = bm + wm * 32 + fi * 16 + lg * 4 + i;
                const int col = bn + wn * 64 + nj * 16 + l15;
                if constexpr (std::is_same<TC, float>::value)
                    C[(long)row * ldc + col] = acc[fi][nj][i];
                else
                    ((unsigned short*)C)[(long)row * ldc + col] = f2bf(acc[fi][nj][i]);
            }
}

// ---------------------------------------------------------------------------
// fp32 -> bf16 bulk convert (n % 2048 == 0 in all uses)
// ---------------------------------------------------------------------------
__global__ __launch_bounds__(256) void cvt_kernel(
    const float* __restrict__ in, bf16* __restrict__ out, long n)
{
    const long i = ((long)blockIdx.x * 256 + threadIdx.x) * 8;
    if (i >= n) return;
    f32x4 a = *(const f32x4*)(in + i), b = *(const f32x4*)(in + i + 4);
    short8 r;
    r[0] = (short)f2bf(a[0]); r[1] = (short)f2bf(a[1]);
    r[2] = (short)f2bf(a[2]); r[3] = (short)f2bf(a[3]);
    r[4] = (short)f2bf(b[0]); r[5] = (short)f2bf(b[1]);
    r[6] = (short)f2bf(b[2]); r[7] = (short)f2bf(b[3]);
    *(short8*)(out + i) = r;
}

// ---------------------------------------------------------------------------
// w_vc [32][512][128] fp32  ->  w_vc^T [32][128][512] bf16
// ---------------------------------------------------------------------------
__global__ __launch_bounds__(256) void tconv_kernel(
    const float* __restrict__ in, bf16* __restrict__ out)
{
    const int h = blockIdx.z, k0 = blockIdx.x * 32, d0 = blockIdx.y * 32;
    __shared__ float t[32][33];
    const int r = threadIdx.x >> 5, c = threadIdx.x & 31;
    const float* ip = in + ((long)h * 512 + k0) * 128 + d0;
    #pragma unroll
    for (int it = 0; it < 4; ++it)
        t[r + 8 * it][c] = ip[(long)(r + 8 * it) * 128 + c];
    __syncthreads();
    bf16* op = out + ((long)h * 128 + d0) * 512 + k0;
    #pragma unroll
    for (int it = 0; it < 4; ++it)
        op[(long)(r + 8 * it) * 512 + c] = __float2bfloat16(t[c][r + 8 * it]);
}

// ---------------------------------------------------------------------------
__global__ __launch_bounds__(256) void rmsnorm_kernel(
    bf16* __restrict__ x, const float* __restrict__ w, int C, int ld)
{
    bf16* row = x + (long)blockIdx.x * ld;
    float ss = 0.f;
    for (int i = threadIdx.x; i < C; i += 256) {
        float v = __bfloat162float(row[i]);
        ss += v * v;
    }
    #pragma unroll
    for (int m = 1; m < 64; m <<= 1) ss += __shfl_xor(ss, m, 64);
    __shared__ float red[4];
    if ((threadIdx.x & 63) == 0) red[threadIdx.x >> 6] = ss;
    __syncthreads();
    ss = red[0] + red[1] + red[2] + red[3];
    float scale = rsqrtf(ss / (float)C + 1e-6f);
    for (int i = threadIdx.x; i < C; i += 256) {
        float v = __bfloat162float(row[i]);
        row[i] = __float2bfloat16(v * scale * w[i]);
    }
}

// ---------------------------------------------------------------------------
__global__ __launch_bounds__(128) void ropeq_kernel(bf16* __restrict__ q)
{
    const int t = blockIdx.x, h = blockIdx.y, i = threadIdx.x;
    bf16* base = q + ((long)t * NH + h) * 192;
    float v = __bfloat162float(base[i]) * SCALE_F;
    if (i < 32) {
        float x1 = __bfloat162float(base[128 + i]);
        float x2 = __bfloat162float(base[160 + i]);
        float inv = powf(10000.f, -(float)i / 32.f);
        float ang = (float)t * inv, s, c;
        sincosf(ang, &s, &c);
        base[128 + i] = __float2bfloat16((x1 * c - x2 * s) * SCALE_F);
        base[160 + i] = __float2bfloat16((x2 * c + x1 * s) * SCALE_F);
    }
    base[i] = __float2bfloat16(v);
}

// ---------------------------------------------------------------------------
// rope k_pe from ckv[:, 512:576] (row stride ld), broadcast into kf[h][t][128:192]
// ---------------------------------------------------------------------------
__global__ __launch_bounds__(64) void ropek_kernel(
    const bf16* __restrict__ ckv, bf16* __restrict__ kf, int ld)
{
    const int t = blockIdx.x, i = threadIdx.x;
    if (i >= 32) return;
    float x1 = __bfloat162float(ckv[(long)t * ld + 512 + i]);
    float x2 = __bfloat162float(ckv[(long)t * ld + 544 + i]);
    float inv = powf(10000.f, -(float)i / 32.f);
    float ang = (float)t * inv, s, c;
    sincosf(ang, &s, &c);
    bf16 o1 = __float2bfloat16(x1 * c - x2 * s);
    bf16 o2 = __float2bfloat16(x2 * c + x1 * s);
    for (int h = 0; h < NH; ++h) {
        bf16* kb = kf + ((long)h * T_SEQ + t) * 192;
        kb[128 + i] = o1;
        kb[160 + i] = o2;
    }
}

// ---------------------------------------------------------------------------
// Flash attention, causal, d=192, dv=128. (unchanged from round 4)
// ---------------------------------------------------------------------------
__global__ __launch_bounds__(256, 2) void attn_kernel(
    const bf16* __restrict__ Q,   // [T][H][192] scaled+roped
    const bf16* __restrict__ Kf,  // [H][T][192]
    const bf16* __restrict__ Vt,  // [H][128][T]  (V^T)
    bf16* __restrict__ O)         // [T][H*128]
{
    const int h = blockIdx.y;
    const int q0 = (gridDim.x - 1 - blockIdx.x) * 128;   // longest blocks first
    const int tid = threadIdx.x, lane = tid & 63, w = tid >> 6;
    const int l15 = lane & 15, lg = lane >> 4;
    const int qw = q0 + w * 32;
    __shared__ __align__(16) short Ks[64 * 192];   // linear, swizzled content
    __shared__ __align__(16) short Vs[128 * 64];

    int ksoff[6];
    #pragma unroll
    for (int j = 0; j < 6; ++j) {
        int o = (w * 6 + j) * 1024 + lane * 16;
        int row = o / 384, col = o % 384;
        ksoff[j] = row * 384 + (col ^ ((row & 7) << 4));
    }
    const int vrow8 = lane >> 3;
    const int vscol = ((lane & 7) * 16) ^ (vrow8 << 4);

    short8 qf[2][6];
    #pragma unroll
    for (int qi = 0; qi < 2; ++qi) {
        const bf16* qp = Q + (long)(qw + qi * 16 + l15) * (NH * 192) + (long)h * 192;
        #pragma unroll
        for (int c = 0; c < 6; ++c) qf[qi][c] = *(const short8*)(qp + c * 32 + lg * 8);
    }

    f32x4 oacc[2][8] = {};
    float mst[2] = {-INFINITY, -INFINITY};
    float lst[2] = {0.f, 0.f};

    const char* kbase0 = (const char*)Kf + (long)h * T_SEQ * 384;
    const char* vbase0 = (const char*)Vt + (long)h * 128 * T_SEQ * 2;
    const int swz = (l15 & 7) << 4;

    for (int s0 = 0; s0 < q0 + 128; s0 += 64) {
        {
            const char* kb = kbase0 + (long)s0 * 384;
            #pragma unroll
            for (int j = 0; j < 6; ++j)
                gload_lds16(kb + ksoff[j], (char*)Ks + (w * 6 + j) * 1024);
            const char* vb = vbase0 + (long)s0 * 2 + vscol;
            #pragma unroll
            for (int j = 0; j < 4; ++j) {
                const int c = w * 4 + j;
                gload_lds16(vb + (long)(c * 8 + vrow8) * (T_SEQ * 2),
                            (char*)Vs + c * 1024);
            }
        }
        __syncthreads();
        if (s0 <= qw + 31) {
            f32x4 st[2][4] = {};
            __builtin_amdgcn_s_setprio(1);
            #pragma unroll
            for (int cb = 0; cb < 4; ++cb) {
                const int krow = cb * 16 + l15;
                #pragma unroll
                for (int c = 0; c < 6; ++c) {
                    short8 kfr = *(const short8*)((const char*)Ks + krow * 384
                                                  + ((c * 64 + lg * 16) ^ swz));
                    st[0][cb] = __builtin_amdgcn_mfma_f32_16x16x32_bf16(kfr, qf[0][c], st[0][cb], 0, 0, 0);
                    st[1][cb] = __builtin_amdgcn_mfma_f32_16x16x32_bf16(kfr, qf[1][c], st[1][cb], 0, 0, 0);
                }
            }
            __builtin_amdgcn_s_setprio(0);
            short8 pb[2][2];
            #pragma unroll
            for (int qi = 0; qi < 2; ++qi) {
                const int qg = qw + qi * 16 + l15;
                float pmax = -INFINITY;
                #pragma unroll
                for (int cb = 0; cb < 4; ++cb)
                    #pragma unroll
                    for (int i = 0; i < 4; ++i) {
                        const int kv = s0 + cb * 16 + lg * 4 + i;
                        float v = (kv <= qg) ? st[qi][cb][i] : -INFINITY;
                        st[qi][cb][i] = v;
                        pmax = fmaxf(pmax, v);
                    }
                pmax = fmaxf(pmax, __shfl_xor(pmax, 16, 64));
                pmax = fmaxf(pmax, __shfl_xor(pmax, 32, 64));
                const float newm = fmaxf(mst[qi], pmax);
                const float mm = (newm == -INFINITY) ? 0.f : newm;
                const float alpha = __expf(mst[qi] - mm);
                float ps = 0.f;
                #pragma unroll
                for (int cb = 0; cb < 4; ++cb)
                    #pragma unroll
                    for (int i = 0; i < 4; ++i) {
                        const float e = __expf(st[qi][cb][i] - mm);
                        st[qi][cb][i] = e; ps += e;
                    }
                ps += __shfl_xor(ps, 16, 64);
                ps += __shfl_xor(ps, 32, 64);
                lst[qi] = lst[qi] * alpha + ps;
                mst[qi] = newm;
                #pragma unroll
                for (int mb = 0; mb < 8; ++mb) oacc[qi][mb] *= alpha;
                #pragma unroll
                for (int hh = 0; hh < 2; ++hh) {
                    unsigned pk[4];
                    #pragma unroll
                    for (int i = 0; i < 4; ++i)
                        pk[i] = (unsigned)f2bf(st[qi][2 * hh][i])
                              | ((unsigned)f2bf(st[qi][2 * hh + 1][i]) << 16);
                    #pragma unroll
                    for (int j = 0; j < 8; ++j) {
                        const int src = l15 + (((2 * lg + (j >> 2)) & 3) << 4);
                        const unsigned u = (unsigned)__shfl((int)pk[j & 3], src, 64);
                        pb[qi][hh][j] = (short)((lg >> 1) ? (u >> 16) : (u & 0xffffu));
                    }
                }
            }
            __builtin_amdgcn_s_setprio(1);
            #pragma unroll
            for (int mb = 0; mb < 8; ++mb) {
                const int vrow = mb * 16 + l15;
                #pragma unroll
                for (int hh = 0; hh < 2; ++hh) {
                    short8 vfr = *(const short8*)((const char*)Vs + vrow * 128
                                                  + ((hh * 64 + lg * 16) ^ swz));
                    oacc[0][mb] = __builtin_amdgcn_mfma_f32_16x16x32_bf16(vfr, pb[0][hh], oacc[0][mb], 0, 0, 0);
                    oacc[1][mb] = __builtin_amdgcn_mfma_f32_16x16x32_bf16(vfr, pb[1][hh], oacc[1][mb], 0, 0, 0);
                }
            }
            __builtin_amdgcn_s_setprio(0);
        }
        __syncthreads();
    }
    #pragma unroll
    for (int qi = 0; qi < 2; ++qi) {
        const float inv = 1.f / lst[qi];
        const int qg = qw + qi * 16 + l15;
        #pragma unroll
        for (int mb = 0; mb < 8; ++mb)
            #pragma unroll
            for (int i = 0; i < 4; ++i) {
                const int dv = mb * 16 + lg * 4 + i;
                O[(long)qg * (NH * 128) + h * 128 + dv] = __float2bfloat16(oacc[qi][mb][i] * inv);
            }
    }
}

// ---------------------------------------------------------------------------
extern "C" void kernel_launch(void* const* d_in, const int* in_sizes, int n_in,
                              void* d_out, int out_size, void* d_ws, size_t ws_size,
                              hipStream_t stream)
{
    const float* hidden    = (const float*)d_in[0];
    const float* w_q_a     = (const float*)d_in[2];
    const float* q_a_ln_w  = (const float*)d_in[3];
    const float* w_q_b     = (const float*)d_in[4];
    const float* w_kv_a    = (const float*)d_in[5];
    const float* kv_a_ln_w = (const float*)d_in[6];
    const float* w_kc      = (const float*)d_in[7];
    const float* w_vc      = (const float*)d_in[8];
    const float* w_o       = (const float*)d_in[9];
    float* out = (float*)d_out;

    // workspace layout (bf16 elements)
    bf16* qckv  = (bf16*)d_ws;                      // [2048][2176]: qa | ckv(640)
    bf16* qbuf  = qckv  + (long)T_SEQ * 2176;       // [2048][32][192]
    bf16* kf    = qbuf  + (long)T_SEQ * 6144;       // [32][2048][192]
    bf16* vt    = kf    + (long)NH * T_SEQ * 192;   // [32][128][2048]  (V^T)
    bf16* ov    = vt    + (long)NH * 128 * T_SEQ;   // [2048][4096]
    bf16* hb    = ov    + (long)T_SEQ * 4096;       // [2048][5120] hidden bf16
    bf16* wqckv = hb    + (long)T_SEQ * 5120;       // [2176][5120]: w_q_a|w_kv_a|pad
    bf16* wqb   = wqckv + (long)2176 * 5120;        // [6144][1536]
    bf16* wkc   = wqb   + (long)6144 * 1536;        // [32][128][512]
    bf16* wvct  = wkc   + (long)NH * 128 * 512;     // [32][128][512]  (w_vc^T)
    bf16* wo    = hb;   // alias: hb/wqckv/wqb region (31M elems) dead by then
    bf16* ckv   = qckv + 1536;                      // ckv rows, stride 2176

    // --- conversions ---
    cvt_kernel<<<dim3(5120), 256, 0, stream>>>(hidden, hb, (long)T_SEQ * 5120);
    cvt_kernel<<<dim3(3840), 256, 0, stream>>>(w_q_a, wqckv, (long)1536 * 5120);
    cvt_kernel<<<dim3(1440), 256, 0, stream>>>(w_kv_a, wqckv + (long)1536 * 5120,
                                               (long)576 * 5120);
    hipMemsetAsync(wqckv + (long)2112 * 5120, 0, (long)64 * 5120 * sizeof(bf16), stream);
    cvt_kernel<<<dim3(4608), 256, 0, stream>>>(w_q_b, wqb, (long)6144 * 1536);
    cvt_kernel<<<dim3(1024), 256, 0, stream>>>(w_kc, wkc, (long)NH * 128 * 512);
    tconv_kernel<<<dim3(16, 4, NH), 256, 0, stream>>>(w_vc, wvct);

    // 1+5 merged: qckv = hb @ wqckv^T   (M=2048, N=2176, K=5120)
    gemm8w_kernel<bf16><<<dim3(17, 16, 1), 512, 0, stream>>>(
        hb, wqckv, qckv, 5120, 5120, 5120, 2176, 0, 0, 0);
    // 2. rmsnorm(qa) — cols 0:1536
    rmsnorm_kernel<<<dim3(T_SEQ), 256, 0, stream>>>(qckv, q_a_ln_w, 1536, 2176);
    // 6. rmsnorm(ckv[:, :512]) — cols 1536:2048
    rmsnorm_kernel<<<dim3(T_SEQ), 256, 0, stream>>>(ckv, kv_a_ln_w, 512, 2176);
    // 3. q = qa @ wqb^T   (M=2048, N=6144, K=1536)
    gemm8w_kernel<bf16><<<dim3(48, 16, 1), 512, 0, stream>>>(
        qckv, wqb, qbuf, 1536, 2176, 1536, 6144, 0, 0, 0);
    // 4. rope+scale q
    ropeq_kernel<<<dim3(T_SEQ, NH), 128, 0, stream>>>(qbuf);
    // 7. rope k_pe -> kf[:,:,128:192]
    ropek_kernel<<<dim3(T_SEQ), 64, 0, stream>>>(ckv, kf, 2176);
    // 8. k_nope[h] = ckv_n @ wkc[h]^T   (batched, M=2048, N=128, K=512)
    gemm8w_kernel<bf16><<<dim3(1, 16, NH), 512, 0, stream>>>(
        ckv, wkc, kf, 512, 2176, 512, 192,
        0, (long)128 * 512, (long)T_SEQ * 192);
    // 9. vt[h] = wvct[h] @ ckv_n^T      (batched, M=128, N=2048, K=512)
    gemm8w_kernel<bf16><<<dim3(16, 1, NH), 512, 0, stream>>>(
        wvct, ckv, vt, 512, 512, 2176, T_SEQ,
        (long)128 * 512, 0, (long)128 * T_SEQ);
    // 10. convert w_o (aliases dead hb/wqckv/wqb region)
    cvt_kernel<<<dim3(10240), 256, 0, stream>>>(w_o, wo, (long)5120 * 4096);
    // 11. attention
    attn_kernel<<<dim3(T_SEQ / 128, NH), 256, 0, stream>>>(qbuf, kf, vt, ov);
    // 12. out = ov @ wo^T   (M=2048, N=5120, K=4096), fp32 out
    gemm8w_kernel<float><<<dim3(40, 16, 1), 512, 0, stream>>>(
        ov, wo, out, 4096, 4096, 4096, 5120, 0, 0, 0);
}

// Round 6
// 528.002 us; speedup vs baseline: 2.1451x; 1.2406x over previous
//
#include <hip/hip_runtime.h>
#include <hip/hip_bf16.h>
#include <type_traits>

typedef __attribute__((ext_vector_type(8))) short short8;
typedef __attribute__((ext_vector_type(4))) float f32x4;
using bf16 = __hip_bfloat16;

#define T_SEQ 2048
#define NH 32
#define SCALE_F 0.07216878364870323f   // 192^-0.5

__device__ inline unsigned short f2bf(float f) {
    unsigned u = __builtin_bit_cast(unsigned, f);
    return (unsigned short)((u + 0x7fffu + ((u >> 16) & 1u)) >> 16);
}

__device__ inline void gload_lds16(const void* g, void* l) {
    __builtin_amdgcn_global_load_lds(
        (const __attribute__((address_space(1))) unsigned*)g,
        (__attribute__((address_space(3))) unsigned*)l, 16, 0, 0);
}

// ---------------------------------------------------------------------------
// Pipelined GEMM: C[M,N] = A[M,K] * B^T (A [M,K], B [N,K] bf16 row-major).
// BM=BN=128, BK=64, 8 waves (512 thr). Double-buffered LDS (64 KB), counted
// vmcnt(4). T2 st-swizzle: LDS rows are 128 B (stride ≡ 0 mod 32 banks), so
// byte-col is XORed with (row&7)<<4 on BOTH sides — pre-swizzled global
// source during staging (LDS dest linear, per rule #21) and swizzled ds_read.
// Requires M%128==0, N%128==0, K%64==0, lda/ldb %8==0.
// ---------------------------------------------------------------------------
template <typename TC>
__global__ __launch_bounds__(512, 4) void gemm8w_kernel(
    const bf16* __restrict__ A, const bf16* __restrict__ B, TC* __restrict__ C,
    int K, int lda, int ldb, int ldc,
    long aStride, long bStride, long cStride)
{
    const int z = blockIdx.z;
    A += (long)z * aStride; B += (long)z * bStride; C += (long)z * cStride;
    const int bm = blockIdx.y * 128, bn = blockIdx.x * 128;
    __shared__ __align__(16) short As[2][128 * 64];
    __shared__ __align__(16) short Bs[2][128 * 64];
    const int tid = threadIdx.x, lane = tid & 63, w = tid >> 6;
    const int l15 = lane & 15, lg = lane >> 4;
    const int wm = w >> 1, wn = w & 1;
    // staging: chunk c = w*2+j covers LDS rows c*8..c*8+7; row&7 == lane>>3
    const int c0 = w * 2, c1 = w * 2 + 1;
    const int srow0 = c0 * 8 + (lane >> 3), srow1 = c1 * 8 + (lane >> 3);
    const int scol = ((lane & 7) * 16) ^ ((lane >> 3) << 4);  // pre-swizzled src col
    const bf16* Ab = A + (long)bm * lda;
    const bf16* Bb = B + (long)bn * ldb;

    auto stage = [&](int buf, int k0) {
        const char* ag = (const char*)(Ab + k0);
        const char* bg = (const char*)(Bb + k0);
        gload_lds16(ag + (long)srow0 * (lda * 2) + scol, &As[buf][c0 * 512]);
        gload_lds16(ag + (long)srow1 * (lda * 2) + scol, &As[buf][c1 * 512]);
        gload_lds16(bg + (long)srow0 * (ldb * 2) + scol, &Bs[buf][c0 * 512]);
        gload_lds16(bg + (long)srow1 * (ldb * 2) + scol, &Bs[buf][c1 * 512]);
    };

    const int swz = (l15 & 7) << 4;   // read-side XOR (row&7 == l15&7)
    f32x4 acc[2][4] = {};
    const int nt = K >> 6;
    stage(0, 0);
    for (int t = 0; t < nt; ++t) {
        if (t + 1 < nt) {
            stage((t + 1) & 1, (t + 1) << 6);
            asm volatile("s_waitcnt vmcnt(4)" ::: "memory");   // this tile done; next in flight
        } else {
            asm volatile("s_waitcnt vmcnt(0)" ::: "memory");
        }
        __builtin_amdgcn_s_barrier();
        __builtin_amdgcn_sched_barrier(0);
        const char* Ap = (const char*)&As[t & 1][0];
        const char* Bp = (const char*)&Bs[t & 1][0];
        short8 af[2][2], bfv[4][2];
        #pragma unroll
        for (int fi = 0; fi < 2; ++fi)
            #pragma unroll
            for (int ks = 0; ks < 2; ++ks)
                af[fi][ks] = *(const short8*)(Ap + (wm * 32 + fi * 16 + l15) * 128
                                              + ((ks * 64 + lg * 16) ^ swz));
        #pragma unroll
        for (int nj = 0; nj < 4; ++nj)
            #pragma unroll
            for (int ks = 0; ks < 2; ++ks)
                bfv[nj][ks] = *(const short8*)(Bp + (wn * 64 + nj * 16 + l15) * 128
                                               + ((ks * 64 + lg * 16) ^ swz));
        #pragma unroll
        for (int ks = 0; ks < 2; ++ks)
            #pragma unroll
            for (int fi = 0; fi < 2; ++fi)
                #pragma unroll
                for (int nj = 0; nj < 4; ++nj)
                    acc[fi][nj] = __builtin_amdgcn_mfma_f32_16x16x32_bf16(
                        af[fi][ks], bfv[nj][ks], acc[fi][nj], 0, 0, 0);
        // all ds_reads must retire before freeing this buffer for overwrite
        asm volatile("s_waitcnt lgkmcnt(0)" ::: "memory");
        __builtin_amdgcn_sched_barrier(0);
        __builtin_amdgcn_s_barrier();
        __builtin_amdgcn_sched_barrier(0);
    }
    #pragma unroll
    for (int fi = 0; fi < 2; ++fi)
        #pragma unroll
        for (int nj = 0; nj < 4; ++nj)
            #pragma unroll
            for (int i = 0; i < 4; ++i) {
                const int row = bm + wm * 32 + fi * 16 + lg * 4 + i;
                const int col = bn + wn * 64 + nj * 16 + l15;
                if constexpr (std::is_same<TC, float>::value)
                    C[(long)row * ldc + col] = acc[fi][nj][i];
                else
                    ((unsigned short*)C)[(long)row * ldc + col] = f2bf(acc[fi][nj][i]);
            }
}

// ---------------------------------------------------------------------------
// fp32 -> bf16 bulk convert (n % 2048 == 0 in all uses)
// ---------------------------------------------------------------------------
__global__ __launch_bounds__(256) void cvt_kernel(
    const float* __restrict__ in, bf16* __restrict__ out, long n)
{
    const long i = ((long)blockIdx.x * 256 + threadIdx.x) * 8;
    if (i >= n) return;
    f32x4 a = *(const f32x4*)(in + i), b = *(const f32x4*)(in + i + 4);
    short8 r;
    r[0] = (short)f2bf(a[0]); r[1] = (short)f2bf(a[1]);
    r[2] = (short)f2bf(a[2]); r[3] = (short)f2bf(a[3]);
    r[4] = (short)f2bf(b[0]); r[5] = (short)f2bf(b[1]);
    r[6] = (short)f2bf(b[2]); r[7] = (short)f2bf(b[3]);
    *(short8*)(out + i) = r;
}

// ---------------------------------------------------------------------------
// w_vc [32][512][128] fp32  ->  w_vc^T [32][128][512] bf16
// ---------------------------------------------------------------------------
__global__ __launch_bounds__(256) void tconv_kernel(
    const float* __restrict__ in, bf16* __restrict__ out)
{
    const int h = blockIdx.z, k0 = blockIdx.x * 32, d0 = blockIdx.y * 32;
    __shared__ float t[32][33];
    const int r = threadIdx.x >> 5, c = threadIdx.x & 31;
    const float* ip = in + ((long)h * 512 + k0) * 128 + d0;
    #pragma unroll
    for (int it = 0; it < 4; ++it)
        t[r + 8 * it][c] = ip[(long)(r + 8 * it) * 128 + c];
    __syncthreads();
    bf16* op = out + ((long)h * 128 + d0) * 512 + k0;
    #pragma unroll
    for (int it = 0; it < 4; ++it)
        op[(long)(r + 8 * it) * 512 + c] = __float2bfloat16(t[c][r + 8 * it]);
}

// ---------------------------------------------------------------------------
__global__ __launch_bounds__(256) void rmsnorm_kernel(
    bf16* __restrict__ x, const float* __restrict__ w, int C, int ld)
{
    bf16* row = x + (long)blockIdx.x * ld;
    float ss = 0.f;
    for (int i = threadIdx.x; i < C; i += 256) {
        float v = __bfloat162float(row[i]);
        ss += v * v;
    }
    #pragma unroll
    for (int m = 1; m < 64; m <<= 1) ss += __shfl_xor(ss, m, 64);
    __shared__ float red[4];
    if ((threadIdx.x & 63) == 0) red[threadIdx.x >> 6] = ss;
    __syncthreads();
    ss = red[0] + red[1] + red[2] + red[3];
    float scale = rsqrtf(ss / (float)C + 1e-6f);
    for (int i = threadIdx.x; i < C; i += 256) {
        float v = __bfloat162float(row[i]);
        row[i] = __float2bfloat16(v * scale * w[i]);
    }
}

// ---------------------------------------------------------------------------
__global__ __launch_bounds__(128) void ropeq_kernel(bf16* __restrict__ q)
{
    const int t = blockIdx.x, h = blockIdx.y, i = threadIdx.x;
    bf16* base = q + ((long)t * NH + h) * 192;
    float v = __bfloat162float(base[i]) * SCALE_F;
    if (i < 32) {
        float x1 = __bfloat162float(base[128 + i]);
        float x2 = __bfloat162float(base[160 + i]);
        float inv = powf(10000.f, -(float)i / 32.f);
        float ang = (float)t * inv, s, c;
        sincosf(ang, &s, &c);
        base[128 + i] = __float2bfloat16((x1 * c - x2 * s) * SCALE_F);
        base[160 + i] = __float2bfloat16((x2 * c + x1 * s) * SCALE_F);
    }
    base[i] = __float2bfloat16(v);
}

// ---------------------------------------------------------------------------
// rope k_pe from ckv[:, 512:576] (row stride ld), broadcast into kf[h][t][128:192]
// ---------------------------------------------------------------------------
__global__ __launch_bounds__(64) void ropek_kernel(
    const bf16* __restrict__ ckv, bf16* __restrict__ kf, int ld)
{
    const int t = blockIdx.x, i = threadIdx.x;
    if (i >= 32) return;
    float x1 = __bfloat162float(ckv[(long)t * ld + 512 + i]);
    float x2 = __bfloat162float(ckv[(long)t * ld + 544 + i]);
    float inv = powf(10000.f, -(float)i / 32.f);
    float ang = (float)t * inv, s, c;
    sincosf(ang, &s, &c);
    bf16 o1 = __float2bfloat16(x1 * c - x2 * s);
    bf16 o2 = __float2bfloat16(x2 * c + x1 * s);
    for (int h = 0; h < NH; ++h) {
        bf16* kb = kf + ((long)h * T_SEQ + t) * 192;
        kb[128 + i] = o1;
        kb[160 + i] = o2;
    }
}

// ---------------------------------------------------------------------------
// Flash attention, causal, d=192, dv=128. (unchanged from round 4)
// ---------------------------------------------------------------------------
__global__ __launch_bounds__(256, 2) void attn_kernel(
    const bf16* __restrict__ Q,   // [T][H][192] scaled+roped
    const bf16* __restrict__ Kf,  // [H][T][192]
    const bf16* __restrict__ Vt,  // [H][128][T]  (V^T)
    bf16* __restrict__ O)         // [T][H*128]
{
    const int h = blockIdx.y;
    const int q0 = (gridDim.x - 1 - blockIdx.x) * 128;   // longest blocks first
    const int tid = threadIdx.x, lane = tid & 63, w = tid >> 6;
    const int l15 = lane & 15, lg = lane >> 4;
    const int qw = q0 + w * 32;
    __shared__ __align__(16) short Ks[64 * 192];   // linear, swizzled content
    __shared__ __align__(16) short Vs[128 * 64];

    int ksoff[6];
    #pragma unroll
    for (int j = 0; j < 6; ++j) {
        int o = (w * 6 + j) * 1024 + lane * 16;
        int row = o / 384, col = o % 384;
        ksoff[j] = row * 384 + (col ^ ((row & 7) << 4));
    }
    const int vrow8 = lane >> 3;
    const int vscol = ((lane & 7) * 16) ^ (vrow8 << 4);

    short8 qf[2][6];
    #pragma unroll
    for (int qi = 0; qi < 2; ++qi) {
        const bf16* qp = Q + (long)(qw + qi * 16 + l15) * (NH * 192) + (long)h * 192;
        #pragma unroll
        for (int c = 0; c < 6; ++c) qf[qi][c] = *(const short8*)(qp + c * 32 + lg * 8);
    }

    f32x4 oacc[2][8] = {};
    float mst[2] = {-INFINITY, -INFINITY};
    float lst[2] = {0.f, 0.f};

    const char* kbase0 = (const char*)Kf + (long)h * T_SEQ * 384;
    const char* vbase0 = (const char*)Vt + (long)h * 128 * T_SEQ * 2;
    const int swz = (l15 & 7) << 4;

    for (int s0 = 0; s0 < q0 + 128; s0 += 64) {
        {
            const char* kb = kbase0 + (long)s0 * 384;
            #pragma unroll
            for (int j = 0; j < 6; ++j)
                gload_lds16(kb + ksoff[j], (char*)Ks + (w * 6 + j) * 1024);
            const char* vb = vbase0 + (long)s0 * 2 + vscol;
            #pragma unroll
            for (int j = 0; j < 4; ++j) {
                const int c = w * 4 + j;
                gload_lds16(vb + (long)(c * 8 + vrow8) * (T_SEQ * 2),
                            (char*)Vs + c * 1024);
            }
        }
        __syncthreads();
        if (s0 <= qw + 31) {
            f32x4 st[2][4] = {};
            __builtin_amdgcn_s_setprio(1);
            #pragma unroll
            for (int cb = 0; cb < 4; ++cb) {
                const int krow = cb * 16 + l15;
                #pragma unroll
                for (int c = 0; c < 6; ++c) {
                    short8 kfr = *(const short8*)((const char*)Ks + krow * 384
                                                  + ((c * 64 + lg * 16) ^ swz));
                    st[0][cb] = __builtin_amdgcn_mfma_f32_16x16x32_bf16(kfr, qf[0][c], st[0][cb], 0, 0, 0);
                    st[1][cb] = __builtin_amdgcn_mfma_f32_16x16x32_bf16(kfr, qf[1][c], st[1][cb], 0, 0, 0);
                }
            }
            __builtin_amdgcn_s_setprio(0);
            short8 pb[2][2];
            #pragma unroll
            for (int qi = 0; qi < 2; ++qi) {
                const int qg = qw + qi * 16 + l15;
                float pmax = -INFINITY;
                #pragma unroll
                for (int cb = 0; cb < 4; ++cb)
                    #pragma unroll
                    for (int i = 0; i < 4; ++i) {
                        const int kv = s0 + cb * 16 + lg * 4 + i;
                        float v = (kv <= qg) ? st[qi][cb][i] : -INFINITY;
                        st[qi][cb][i] = v;
                        pmax = fmaxf(pmax, v);
                    }
                pmax = fmaxf(pmax, __shfl_xor(pmax, 16, 64));
                pmax = fmaxf(pmax, __shfl_xor(pmax, 32, 64));
                const float newm = fmaxf(mst[qi], pmax);
                const float mm = (newm == -INFINITY) ? 0.f : newm;
                const float alpha = __expf(mst[qi] - mm);
                float ps = 0.f;
                #pragma unroll
                for (int cb = 0; cb < 4; ++cb)
                    #pragma unroll
                    for (int i = 0; i < 4; ++i) {
                        const float e = __expf(st[qi][cb][i] - mm);
                        st[qi][cb][i] = e; ps += e;
                    }
                ps += __shfl_xor(ps, 16, 64);
                ps += __shfl_xor(ps, 32, 64);
                lst[qi] = lst[qi] * alpha + ps;
                mst[qi] = newm;
                #pragma unroll
                for (int mb = 0; mb < 8; ++mb) oacc[qi][mb] *= alpha;
                #pragma unroll
                for (int hh = 0; hh < 2; ++hh) {
                    unsigned pk[4];
                    #pragma unroll
                    for (int i = 0; i < 4; ++i)
                        pk[i] = (unsigned)f2bf(st[qi][2 * hh][i])
                              | ((unsigned)f2bf(st[qi][2 * hh + 1][i]) << 16);
                    #pragma unroll
                    for (int j = 0; j < 8; ++j) {
                        const int src = l15 + (((2 * lg + (j >> 2)) & 3) << 4);
                        const unsigned u = (unsigned)__shfl((int)pk[j & 3], src, 64);
                        pb[qi][hh][j] = (short)((lg >> 1) ? (u >> 16) : (u & 0xffffu));
                    }
                }
            }
            __builtin_amdgcn_s_setprio(1);
            #pragma unroll
            for (int mb = 0; mb < 8; ++mb) {
                const int vrow = mb * 16 + l15;
                #pragma unroll
                for (int hh = 0; hh < 2; ++hh) {
                    short8 vfr = *(const short8*)((const char*)Vs + vrow * 128
                                                  + ((hh * 64 + lg * 16) ^ swz));
                    oacc[0][mb] = __builtin_amdgcn_mfma_f32_16x16x32_bf16(vfr, pb[0][hh], oacc[0][mb], 0, 0, 0);
                    oacc[1][mb] = __builtin_amdgcn_mfma_f32_16x16x32_bf16(vfr, pb[1][hh], oacc[1][mb], 0, 0, 0);
                }
            }
            __builtin_amdgcn_s_setprio(0);
        }
        __syncthreads();
    }
    #pragma unroll
    for (int qi = 0; qi < 2; ++qi) {
        const float inv = 1.f / lst[qi];
        const int qg = qw + qi * 16 + l15;
        #pragma unroll
        for (int mb = 0; mb < 8; ++mb)
            #pragma unroll
            for (int i = 0; i < 4; ++i) {
                const int dv = mb * 16 + lg * 4 + i;
                O[(long)qg * (NH * 128) + h * 128 + dv] = __float2bfloat16(oacc[qi][mb][i] * inv);
            }
    }
}

// ---------------------------------------------------------------------------
extern "C" void kernel_launch(void* const* d_in, const int* in_sizes, int n_in,
                              void* d_out, int out_size, void* d_ws, size_t ws_size,
                              hipStream_t stream)
{
    const float* hidden    = (const float*)d_in[0];
    const float* w_q_a     = (const float*)d_in[2];
    const float* q_a_ln_w  = (const float*)d_in[3];
    const float* w_q_b     = (const float*)d_in[4];
    const float* w_kv_a    = (const float*)d_in[5];
    const float* kv_a_ln_w = (const float*)d_in[6];
    const float* w_kc      = (const float*)d_in[7];
    const float* w_vc      = (const float*)d_in[8];
    const float* w_o       = (const float*)d_in[9];
    float* out = (float*)d_out;

    // workspace layout (bf16 elements)
    bf16* qckv  = (bf16*)d_ws;                      // [2048][2176]: qa | ckv(640)
    bf16* qbuf  = qckv  + (long)T_SEQ * 2176;       // [2048][32][192]
    bf16* kf    = qbuf  + (long)T_SEQ * 6144;       // [32][2048][192]
    bf16* vt    = kf    + (long)NH * T_SEQ * 192;   // [32][128][2048]  (V^T)
    bf16* ov    = vt    + (long)NH * 128 * T_SEQ;   // [2048][4096]
    bf16* hb    = ov    + (long)T_SEQ * 4096;       // [2048][5120] hidden bf16
    bf16* wqckv = hb    + (long)T_SEQ * 5120;       // [2176][5120]: w_q_a|w_kv_a|pad
    bf16* wqb   = wqckv + (long)2176 * 5120;        // [6144][1536]
    bf16* wkc   = wqb   + (long)6144 * 1536;        // [32][128][512]
    bf16* wvct  = wkc   + (long)NH * 128 * 512;     // [32][128][512]  (w_vc^T)
    bf16* wo    = hb;   // alias: hb/wqckv/wqb region (31M elems) dead by then
    bf16* ckv   = qckv + 1536;                      // ckv rows, stride 2176

    // --- conversions ---
    cvt_kernel<<<dim3(5120), 256, 0, stream>>>(hidden, hb, (long)T_SEQ * 5120);
    cvt_kernel<<<dim3(3840), 256, 0, stream>>>(w_q_a, wqckv, (long)1536 * 5120);
    cvt_kernel<<<dim3(1440), 256, 0, stream>>>(w_kv_a, wqckv + (long)1536 * 5120,
                                               (long)576 * 5120);
    hipMemsetAsync(wqckv + (long)2112 * 5120, 0, (long)64 * 5120 * sizeof(bf16), stream);
    cvt_kernel<<<dim3(4608), 256, 0, stream>>>(w_q_b, wqb, (long)6144 * 1536);
    cvt_kernel<<<dim3(1024), 256, 0, stream>>>(w_kc, wkc, (long)NH * 128 * 512);
    tconv_kernel<<<dim3(16, 4, NH), 256, 0, stream>>>(w_vc, wvct);

    // 1+5 merged: qckv = hb @ wqckv^T   (M=2048, N=2176, K=5120)
    gemm8w_kernel<bf16><<<dim3(17, 16, 1), 512, 0, stream>>>(
        hb, wqckv, qckv, 5120, 5120, 5120, 2176, 0, 0, 0);
    // 2. rmsnorm(qa) — cols 0:1536
    rmsnorm_kernel<<<dim3(T_SEQ), 256, 0, stream>>>(qckv, q_a_ln_w, 1536, 2176);
    // 6. rmsnorm(ckv[:, :512]) — cols 1536:2048
    rmsnorm_kernel<<<dim3(T_SEQ), 256, 0, stream>>>(ckv, kv_a_ln_w, 512, 2176);
    // 3. q = qa @ wqb^T   (M=2048, N=6144, K=1536)
    gemm8w_kernel<bf16><<<dim3(48, 16, 1), 512, 0, stream>>>(
        qckv, wqb, qbuf, 1536, 2176, 1536, 6144, 0, 0, 0);
    // 4. rope+scale q
    ropeq_kernel<<<dim3(T_SEQ, NH), 128, 0, stream>>>(qbuf);
    // 7. rope k_pe -> kf[:,:,128:192]
    ropek_kernel<<<dim3(T_SEQ), 64, 0, stream>>>(ckv, kf, 2176);
    // 8. k_nope[h] = ckv_n @ wkc[h]^T   (batched, M=2048, N=128, K=512)
    gemm8w_kernel<bf16><<<dim3(1, 16, NH), 512, 0, stream>>>(
        ckv, wkc, kf, 512, 2176, 512, 192,
        0, (long)128 * 512, (long)T_SEQ * 192);
    // 9. vt[h] = wvct[h] @ ckv_n^T      (batched, M=128, N=2048, K=512)
    gemm8w_kernel<bf16><<<dim3(16, 1, NH), 512, 0, stream>>>(
        wvct, ckv, vt, 512, 512, 2176, T_SEQ,
        (long)128 * 512, 0, (long)128 * T_SEQ);
    // 10. convert w_o (aliases dead hb/wqckv/wqb region)
    cvt_kernel<<<dim3(10240), 256, 0, stream>>>(w_o, wo, (long)5120 * 4096);
    // 11. attention
    attn_kernel<<<dim3(T_SEQ / 128, NH), 256, 0, stream>>>(qbuf, kf, vt, ov);
    // 12. out = ov @ wo^T   (M=2048, N=5120, K=4096), fp32 out
    gemm8w_kernel<float><<<dim3(40, 16, 1), 512, 0, stream>>>(
        ov, wo, out, 4096, 4096, 4096, 5120, 0, 0, 0);
}

// Round 7
// 527.538 us; speedup vs baseline: 2.1469x; 1.0009x over previous
//
#include <hip/hip_runtime.h>
#include <hip/hip_bf16.h>
#include <type_traits>

typedef __attribute__((ext_vector_type(8))) short short8;
typedef __attribute__((ext_vector_type(4))) float f32x4;
using bf16 = __hip_bfloat16;

#define T_SEQ 2048
#define NH 32
#define SCALE_F 0.07216878364870323f   // 192^-0.5

__device__ inline unsigned short f2bf(float f) {
    unsigned u = __builtin_bit_cast(unsigned, f);
    return (unsigned short)((u + 0x7fffu + ((u >> 16) & 1u)) >> 16);
}

__device__ inline void gload_lds16(const void* g, void* l) {
    __builtin_amdgcn_global_load_lds(
        (const __attribute__((address_space(1))) unsigned*)g,
        (__attribute__((address_space(3))) unsigned*)l, 16, 0, 0);
}

// ---------------------------------------------------------------------------
// Pipelined GEMM (unchanged from round 6): C[M,N] = A[M,K] * B^T, bf16.
// BM=BN=128, BK=64, 8 waves, dbuf LDS, counted vmcnt(4), T2 both-sides swizzle.
// ---------------------------------------------------------------------------
template <typename TC>
__global__ __launch_bounds__(512, 4) void gemm8w_kernel(
    const bf16* __restrict__ A, const bf16* __restrict__ B, TC* __restrict__ C,
    int K, int lda, int ldb, int ldc,
    long aStride, long bStride, long cStride)
{
    const int z = blockIdx.z;
    A += (long)z * aStride; B += (long)z * bStride; C += (long)z * cStride;
    const int bm = blockIdx.y * 128, bn = blockIdx.x * 128;
    __shared__ __align__(16) short As[2][128 * 64];
    __shared__ __align__(16) short Bs[2][128 * 64];
    const int tid = threadIdx.x, lane = tid & 63, w = tid >> 6;
    const int l15 = lane & 15, lg = lane >> 4;
    const int wm = w >> 1, wn = w & 1;
    const int c0 = w * 2, c1 = w * 2 + 1;
    const int srow0 = c0 * 8 + (lane >> 3), srow1 = c1 * 8 + (lane >> 3);
    const int scol = ((lane & 7) * 16) ^ ((lane >> 3) << 4);
    const bf16* Ab = A + (long)bm * lda;
    const bf16* Bb = B + (long)bn * ldb;

    auto stage = [&](int buf, int k0) {
        const char* ag = (const char*)(Ab + k0);
        const char* bg = (const char*)(Bb + k0);
        gload_lds16(ag + (long)srow0 * (lda * 2) + scol, &As[buf][c0 * 512]);
        gload_lds16(ag + (long)srow1 * (lda * 2) + scol, &As[buf][c1 * 512]);
        gload_lds16(bg + (long)srow0 * (ldb * 2) + scol, &Bs[buf][c0 * 512]);
        gload_lds16(bg + (long)srow1 * (ldb * 2) + scol, &Bs[buf][c1 * 512]);
    };

    const int swz = (l15 & 7) << 4;
    f32x4 acc[2][4] = {};
    const int nt = K >> 6;
    stage(0, 0);
    for (int t = 0; t < nt; ++t) {
        if (t + 1 < nt) {
            stage((t + 1) & 1, (t + 1) << 6);
            asm volatile("s_waitcnt vmcnt(4)" ::: "memory");
        } else {
            asm volatile("s_waitcnt vmcnt(0)" ::: "memory");
        }
        __builtin_amdgcn_s_barrier();
        __builtin_amdgcn_sched_barrier(0);
        const char* Ap = (const char*)&As[t & 1][0];
        const char* Bp = (const char*)&Bs[t & 1][0];
        short8 af[2][2], bfv[4][2];
        #pragma unroll
        for (int fi = 0; fi < 2; ++fi)
            #pragma unroll
            for (int ks = 0; ks < 2; ++ks)
                af[fi][ks] = *(const short8*)(Ap + (wm * 32 + fi * 16 + l15) * 128
                                              + ((ks * 64 + lg * 16) ^ swz));
        #pragma unroll
        for (int nj = 0; nj < 4; ++nj)
            #pragma unroll
            for (int ks = 0; ks < 2; ++ks)
                bfv[nj][ks] = *(const short8*)(Bp + (wn * 64 + nj * 16 + l15) * 128
                                               + ((ks * 64 + lg * 16) ^ swz));
        #pragma unroll
        for (int ks = 0; ks < 2; ++ks)
            #pragma unroll
            for (int fi = 0; fi < 2; ++fi)
                #pragma unroll
                for (int nj = 0; nj < 4; ++nj)
                    acc[fi][nj] = __builtin_amdgcn_mfma_f32_16x16x32_bf16(
                        af[fi][ks], bfv[nj][ks], acc[fi][nj], 0, 0, 0);
        asm volatile("s_waitcnt lgkmcnt(0)" ::: "memory");
        __builtin_amdgcn_sched_barrier(0);
        __builtin_amdgcn_s_barrier();
        __builtin_amdgcn_sched_barrier(0);
    }
    #pragma unroll
    for (int fi = 0; fi < 2; ++fi)
        #pragma unroll
        for (int nj = 0; nj < 4; ++nj)
            #pragma unroll
            for (int i = 0; i < 4; ++i) {
                const int row = bm + wm * 32 + fi * 16 + lg * 4 + i;
                const int col = bn + wn * 64 + nj * 16 + l15;
                if constexpr (std::is_same<TC, float>::value)
                    C[(long)row * ldc + col] = acc[fi][nj][i];
                else
                    ((unsigned short*)C)[(long)row * ldc + col] = f2bf(acc[fi][nj][i]);
            }
}

// ---------------------------------------------------------------------------
// fp32 -> bf16 bulk convert with optional scale (n % 2048 == 0)
// ---------------------------------------------------------------------------
__global__ __launch_bounds__(256) void cvt_kernel(
    const float* __restrict__ in, bf16* __restrict__ out, long n, float scale)
{
    const long i = ((long)blockIdx.x * 256 + threadIdx.x) * 8;
    if (i >= n) return;
    f32x4 a = *(const f32x4*)(in + i), b = *(const f32x4*)(in + i + 4);
    short8 r;
    r[0] = (short)f2bf(a[0] * scale); r[1] = (short)f2bf(a[1] * scale);
    r[2] = (short)f2bf(a[2] * scale); r[3] = (short)f2bf(a[3] * scale);
    r[4] = (short)f2bf(b[0] * scale); r[5] = (short)f2bf(b[1] * scale);
    r[6] = (short)f2bf(b[2] * scale); r[7] = (short)f2bf(b[3] * scale);
    *(short8*)(out + i) = r;
}

// ---------------------------------------------------------------------------
// w_vc [32][512][128] fp32  ->  w_vc^T [32][128][512] bf16
// ---------------------------------------------------------------------------
__global__ __launch_bounds__(256) void tconv_kernel(
    const float* __restrict__ in, bf16* __restrict__ out)
{
    const int h = blockIdx.z, k0 = blockIdx.x * 32, d0 = blockIdx.y * 32;
    __shared__ float t[32][33];
    const int r = threadIdx.x >> 5, c = threadIdx.x & 31;
    const float* ip = in + ((long)h * 512 + k0) * 128 + d0;
    #pragma unroll
    for (int it = 0; it < 4; ++it)
        t[r + 8 * it][c] = ip[(long)(r + 8 * it) * 128 + c];
    __syncthreads();
    bf16* op = out + ((long)h * 128 + d0) * 512 + k0;
    #pragma unroll
    for (int it = 0; it < 4; ++it)
        op[(long)(r + 8 * it) * 512 + c] = __float2bfloat16(t[c][r + 8 * it]);
}

// ---------------------------------------------------------------------------
__global__ __launch_bounds__(256) void rmsnorm_kernel(
    bf16* __restrict__ x, const float* __restrict__ w, int C, int ld)
{
    bf16* row = x + (long)blockIdx.x * ld;
    float ss = 0.f;
    for (int i = threadIdx.x; i < C; i += 256) {
        float v = __bfloat162float(row[i]);
        ss += v * v;
    }
    #pragma unroll
    for (int m = 1; m < 64; m <<= 1) ss += __shfl_xor(ss, m, 64);
    __shared__ float red[4];
    if ((threadIdx.x & 63) == 0) red[threadIdx.x >> 6] = ss;
    __syncthreads();
    ss = red[0] + red[1] + red[2] + red[3];
    float scale = rsqrtf(ss / (float)C + 1e-6f);
    for (int i = threadIdx.x; i < C; i += 256) {
        float v = __bfloat162float(row[i]);
        row[i] = __float2bfloat16(v * scale * w[i]);
    }
}

// ---------------------------------------------------------------------------
// rope q (SCALE already folded into w_q_b conversion): only the 64 rope dims
// per (t,h). grid T_SEQ x 256 threads; 4 (h,i) pairs per thread.
// ---------------------------------------------------------------------------
__global__ __launch_bounds__(256) void ropeq_kernel(bf16* __restrict__ q)
{
    const int t = blockIdx.x;
    #pragma unroll
    for (int it = 0; it < 4; ++it) {
        const int pair = threadIdx.x + 256 * it;
        const int h = pair >> 5, i = pair & 31;
        bf16* base = q + ((long)t * NH + h) * 192;
        float x1 = __bfloat162float(base[128 + i]);
        float x2 = __bfloat162float(base[160 + i]);
        float inv = powf(10000.f, -(float)i / 32.f);
        float ang = (float)t * inv, s, c;
        sincosf(ang, &s, &c);
        base[128 + i] = __float2bfloat16(x1 * c - x2 * s);
        base[160 + i] = __float2bfloat16(x2 * c + x1 * s);
    }
}

// ---------------------------------------------------------------------------
// rope k_pe -> kf[h][t][128:192]. grid T_SEQ x 1024 threads, one (h,i) each.
// ---------------------------------------------------------------------------
__global__ __launch_bounds__(1024) void ropek_kernel(
    const bf16* __restrict__ ckv, bf16* __restrict__ kf, int ld)
{
    const int t = blockIdx.x;
    const int h = threadIdx.x >> 5, i = threadIdx.x & 31;
    float x1 = __bfloat162float(ckv[(long)t * ld + 512 + i]);
    float x2 = __bfloat162float(ckv[(long)t * ld + 544 + i]);
    float inv = powf(10000.f, -(float)i / 32.f);
    float ang = (float)t * inv, s, c;
    sincosf(ang, &s, &c);
    bf16* kb = kf + ((long)h * T_SEQ + t) * 192;
    kb[128 + i] = __float2bfloat16(x1 * c - x2 * s);
    kb[160 + i] = __float2bfloat16(x2 * c + x1 * s);
}

// ---------------------------------------------------------------------------
// Flash attention, causal, d=192, dv=128. 4 waves x 32 q-rows, KVBLK=64.
// T14 async-STAGE: K/V prefetched into registers (issued right after the LDS
// write of the current tile, so HBM latency hides under QK+softmax+PV), then
// written to LDS with directly-swizzled ds_write_b128 (same XOR involution as
// the reads). Single 40KB LDS buffer. Loop-top __syncthreads() doubles as the
// vmcnt(0) for the prefetched regs; mid-loop barrier is raw s_barrier +
// lgkmcnt(0) so the just-issued next-tile loads stay in flight.
// Grid: 1-D 512 blocks; decode gives same-head -> same XCD (id mod 8) and
// complementary causal lengths for block pairs (i, i+256).
// ---------------------------------------------------------------------------
__global__ __launch_bounds__(256, 2) void attn_kernel(
    const bf16* __restrict__ Q,   // [T][H][192] scaled+roped
    const bf16* __restrict__ Kf,  // [H][T][192]
    const bf16* __restrict__ Vt,  // [H][128][T]  (V^T)
    bf16* __restrict__ O)         // [T][H*128]
{
    const int lin = blockIdx.x;
    const int h = (lin & 7) + 8 * ((lin >> 3) & 3);
    const int qraw = lin >> 5;
    const int qblk = (qraw < 8) ? (2 * qraw) : (31 - 2 * qraw);
    const int q0 = qblk * 128;
    const int tid = threadIdx.x, lane = tid & 63, w = tid >> 6;
    const int l15 = lane & 15, lg = lane >> 4;
    const int qw = q0 + w * 32;
    __shared__ __align__(16) short Ks[64 * 192];
    __shared__ __align__(16) short Vs[128 * 64];

    // swizzled LDS write destinations (bytes)
    int kdst[6];
    #pragma unroll
    for (int j = 0; j < 6; ++j) {
        int o = (w * 6 + j) * 1024 + lane * 16;
        int row = o / 384, col = o % 384;
        kdst[j] = row * 384 + (col ^ ((row & 7) << 4));
    }
    const int vrow8 = lane >> 3;
    const int vcol = (lane & 7) * 16;
    const int vdst = vrow8 * 128 + (vcol ^ (vrow8 << 4));

    short8 qf[2][6];
    #pragma unroll
    for (int qi = 0; qi < 2; ++qi) {
        const bf16* qp = Q + (long)(qw + qi * 16 + l15) * (NH * 192) + (long)h * 192;
        #pragma unroll
        for (int c = 0; c < 6; ++c) qf[qi][c] = *(const short8*)(qp + c * 32 + lg * 8);
    }

    f32x4 oacc[2][8] = {};
    float mst[2] = {-INFINITY, -INFINITY};
    float lst[2] = {0.f, 0.f};

    const char* kbase0 = (const char*)Kf + (long)h * T_SEQ * 384;
    const char* vbase0 = (const char*)Vt + (long)h * 128 * (T_SEQ * 2);
    const int swz = (l15 & 7) << 4;

    const int nt = (q0 + 128) >> 6;
    f32x4 kreg[6], vreg[4];
    auto issue = [&](int s0) {
        const char* kb = kbase0 + (long)s0 * 384;
        #pragma unroll
        for (int j = 0; j < 6; ++j)
            kreg[j] = *(const f32x4*)(kb + (w * 6 + j) * 1024 + lane * 16);
        const char* vb = vbase0 + (long)s0 * 2 + vcol;
        #pragma unroll
        for (int j = 0; j < 4; ++j)
            vreg[j] = *(const f32x4*)(vb + (long)((w * 4 + j) * 8 + vrow8) * (T_SEQ * 2));
    };

    issue(0);
    for (int t = 0; t < nt; ++t) {
        const int s0 = t * 64;
        __syncthreads();   // vmcnt(0): tile-t regs ready; all prior LDS reads done
        #pragma unroll
        for (int j = 0; j < 6; ++j)
            *(f32x4*)((char*)Ks + kdst[j]) = kreg[j];
        #pragma unroll
        for (int j = 0; j < 4; ++j)
            *(f32x4*)((char*)Vs + (w * 4 + j) * 1024 + vdst) = vreg[j];
        if (t + 1 < nt) issue(s0 + 64);
        asm volatile("" ::: "memory");
        asm volatile("s_waitcnt lgkmcnt(0)" ::: "memory");   // ds_writes drained
        __builtin_amdgcn_sched_barrier(0);
        __builtin_amdgcn_s_barrier();                        // vmcnt NOT drained
        if (s0 <= qw + 31) {
            f32x4 st[2][4] = {};
            __builtin_amdgcn_s_setprio(1);
            #pragma unroll
            for (int cb = 0; cb < 4; ++cb) {
                const int krow = cb * 16 + l15;
                #pragma unroll
                for (int c = 0; c < 6; ++c) {
                    short8 kfr = *(const short8*)((const char*)Ks + krow * 384
                                                  + ((c * 64 + lg * 16) ^ swz));
                    st[0][cb] = __builtin_amdgcn_mfma_f32_16x16x32_bf16(kfr, qf[0][c], st[0][cb], 0, 0, 0);
                    st[1][cb] = __builtin_amdgcn_mfma_f32_16x16x32_bf16(kfr, qf[1][c], st[1][cb], 0, 0, 0);
                }
            }
            __builtin_amdgcn_s_setprio(0);
            short8 pb[2][2];
            #pragma unroll
            for (int qi = 0; qi < 2; ++qi) {
                const int qg = qw + qi * 16 + l15;
                float pmax = -INFINITY;
                #pragma unroll
                for (int cb = 0; cb < 4; ++cb)
                    #pragma unroll
                    for (int i = 0; i < 4; ++i) {
                        const int kv = s0 + cb * 16 + lg * 4 + i;
                        float v = (kv <= qg) ? st[qi][cb][i] : -INFINITY;
                        st[qi][cb][i] = v;
                        pmax = fmaxf(pmax, v);
                    }
                pmax = fmaxf(pmax, __shfl_xor(pmax, 16, 64));
                pmax = fmaxf(pmax, __shfl_xor(pmax, 32, 64));
                const float newm = fmaxf(mst[qi], pmax);
                const float mm = (newm == -INFINITY) ? 0.f : newm;
                const float alpha = __expf(mst[qi] - mm);
                float ps = 0.f;
                #pragma unroll
                for (int cb = 0; cb < 4; ++cb)
                    #pragma unroll
                    for (int i = 0; i < 4; ++i) {
                        const float e = __expf(st[qi][cb][i] - mm);
                        st[qi][cb][i] = e; ps += e;
                    }
                ps += __shfl_xor(ps, 16, 64);
                ps += __shfl_xor(ps, 32, 64);
                lst[qi] = lst[qi] * alpha + ps;
                mst[qi] = newm;
                #pragma unroll
                for (int mb = 0; mb < 8; ++mb) oacc[qi][mb] *= alpha;
                #pragma unroll
                for (int hh = 0; hh < 2; ++hh) {
                    unsigned pk[4];
                    #pragma unroll
                    for (int i = 0; i < 4; ++i)
                        pk[i] = (unsigned)f2bf(st[qi][2 * hh][i])
                              | ((unsigned)f2bf(st[qi][2 * hh + 1][i]) << 16);
                    #pragma unroll
                    for (int j = 0; j < 8; ++j) {
                        const int src = l15 + (((2 * lg + (j >> 2)) & 3) << 4);
                        const unsigned u = (unsigned)__shfl((int)pk[j & 3], src, 64);
                        pb[qi][hh][j] = (short)((lg >> 1) ? (u >> 16) : (u & 0xffffu));
                    }
                }
            }
            __builtin_amdgcn_s_setprio(1);
            #pragma unroll
            for (int mb = 0; mb < 8; ++mb) {
                const int vrow = mb * 16 + l15;
                #pragma unroll
                for (int hh = 0; hh < 2; ++hh) {
                    short8 vfr = *(const short8*)((const char*)Vs + vrow * 128
                                                  + ((hh * 64 + lg * 16) ^ swz));
                    oacc[0][mb] = __builtin_amdgcn_mfma_f32_16x16x32_bf16(vfr, pb[0][hh], oacc[0][mb], 0, 0, 0);
                    oacc[1][mb] = __builtin_amdgcn_mfma_f32_16x16x32_bf16(vfr, pb[1][hh], oacc[1][mb], 0, 0, 0);
                }
            }
            __builtin_amdgcn_s_setprio(0);
        }
    }
    #pragma unroll
    for (int qi = 0; qi < 2; ++qi) {
        const float inv = 1.f / lst[qi];
        const int qg = qw + qi * 16 + l15;
        #pragma unroll
        for (int mb = 0; mb < 8; ++mb)
            #pragma unroll
            for (int i = 0; i < 4; ++i) {
                const int dv = mb * 16 + lg * 4 + i;
                O[(long)qg * (NH * 128) + h * 128 + dv] = __float2bfloat16(oacc[qi][mb][i] * inv);
            }
    }
}

// ---------------------------------------------------------------------------
extern "C" void kernel_launch(void* const* d_in, const int* in_sizes, int n_in,
                              void* d_out, int out_size, void* d_ws, size_t ws_size,
                              hipStream_t stream)
{
    const float* hidden    = (const float*)d_in[0];
    const float* w_q_a     = (const float*)d_in[2];
    const float* q_a_ln_w  = (const float*)d_in[3];
    const float* w_q_b     = (const float*)d_in[4];
    const float* w_kv_a    = (const float*)d_in[5];
    const float* kv_a_ln_w = (const float*)d_in[6];
    const float* w_kc      = (const float*)d_in[7];
    const float* w_vc      = (const float*)d_in[8];
    const float* w_o       = (const float*)d_in[9];
    float* out = (float*)d_out;

    // workspace layout (bf16 elements)
    bf16* qckv  = (bf16*)d_ws;                      // [2048][2176]: qa | ckv(640)
    bf16* qbuf  = qckv  + (long)T_SEQ * 2176;       // [2048][32][192]
    bf16* kf    = qbuf  + (long)T_SEQ * 6144;       // [32][2048][192]
    bf16* vt    = kf    + (long)NH * T_SEQ * 192;   // [32][128][2048]  (V^T)
    bf16* ov    = vt    + (long)NH * 128 * T_SEQ;   // [2048][4096]
    bf16* hb    = ov    + (long)T_SEQ * 4096;       // [2048][5120] hidden bf16
    bf16* wqckv = hb    + (long)T_SEQ * 5120;       // [2176][5120]: w_q_a|w_kv_a|pad
    bf16* wqb   = wqckv + (long)2176 * 5120;        // [6144][1536]
    bf16* wkc   = wqb   + (long)6144 * 1536;        // [32][128][512]
    bf16* wvct  = wkc   + (long)NH * 128 * 512;     // [32][128][512]  (w_vc^T)
    bf16* wo    = hb;   // alias: hb/wqckv/wqb region dead by then
    bf16* ckv   = qckv + 1536;                      // ckv rows, stride 2176

    // --- conversions ---
    cvt_kernel<<<dim3(5120), 256, 0, stream>>>(hidden, hb, (long)T_SEQ * 5120, 1.f);
    cvt_kernel<<<dim3(3840), 256, 0, stream>>>(w_q_a, wqckv, (long)1536 * 5120, 1.f);
    cvt_kernel<<<dim3(1440), 256, 0, stream>>>(w_kv_a, wqckv + (long)1536 * 5120,
                                               (long)576 * 5120, 1.f);
    hipMemsetAsync(wqckv + (long)2112 * 5120, 0, (long)64 * 5120 * sizeof(bf16), stream);
    // SCALE folded into w_q_b (q = qa @ (SCALE*wqb)^T)
    cvt_kernel<<<dim3(4608), 256, 0, stream>>>(w_q_b, wqb, (long)6144 * 1536, SCALE_F);
    cvt_kernel<<<dim3(1024), 256, 0, stream>>>(w_kc, wkc, (long)NH * 128 * 512, 1.f);
    tconv_kernel<<<dim3(16, 4, NH), 256, 0, stream>>>(w_vc, wvct);

    // 1+5 merged: qckv = hb @ wqckv^T   (M=2048, N=2176, K=5120)
    gemm8w_kernel<bf16><<<dim3(17, 16, 1), 512, 0, stream>>>(
        hb, wqckv, qckv, 5120, 5120, 5120, 2176, 0, 0, 0);
    // 2. rmsnorm(qa) — cols 0:1536
    rmsnorm_kernel<<<dim3(T_SEQ), 256, 0, stream>>>(qckv, q_a_ln_w, 1536, 2176);
    // 6. rmsnorm(ckv[:, :512]) — cols 1536:2048
    rmsnorm_kernel<<<dim3(T_SEQ), 256, 0, stream>>>(ckv, kv_a_ln_w, 512, 2176);
    // 3. q = qa @ wqb^T   (M=2048, N=6144, K=1536)
    gemm8w_kernel<bf16><<<dim3(48, 16, 1), 512, 0, stream>>>(
        qckv, wqb, qbuf, 1536, 2176, 1536, 6144, 0, 0, 0);
    // 4. rope q (rope dims only; SCALE already applied)
    ropeq_kernel<<<dim3(T_SEQ), 256, 0, stream>>>(qbuf);
    // 7. rope k_pe -> kf[:,:,128:192]
    ropek_kernel<<<dim3(T_SEQ), 1024, 0, stream>>>(ckv, kf, 2176);
    // 8. k_nope[h] = ckv_n @ wkc[h]^T   (batched, M=2048, N=128, K=512)
    gemm8w_kernel<bf16><<<dim3(1, 16, NH), 512, 0, stream>>>(
        ckv, wkc, kf, 512, 2176, 512, 192,
        0, (long)128 * 512, (long)T_SEQ * 192);
    // 9. vt[h] = wvct[h] @ ckv_n^T      (batched, M=128, N=2048, K=512)
    gemm8w_kernel<bf16><<<dim3(16, 1, NH), 512, 0, stream>>>(
        wvct, ckv, vt, 512, 512, 2176, T_SEQ,
        (long)128 * 512, 0, (long)128 * T_SEQ);
    // 10. convert w_o (aliases dead region)
    cvt_kernel<<<dim3(10240), 256, 0, stream>>>(w_o, wo, (long)5120 * 4096, 1.f);
    // 11. attention (1-D grid: XCD-grouped heads + complementary-length pairs)
    attn_kernel<<<dim3(512), 256, 0, stream>>>(qbuf, kf, vt, ov);
    // 12. out = ov @ wo^T   (M=2048, N=5120, K=4096), fp32 out
    gemm8w_kernel<float><<<dim3(40, 16, 1), 512, 0, stream>>>(
        ov, wo, out, 4096, 4096, 4096, 5120, 0, 0, 0);
}

// Round 8
// 486.482 us; speedup vs baseline: 2.3281x; 1.0844x over previous
//
#include <hip/hip_runtime.h>
#include <hip/hip_bf16.h>
#include <type_traits>

typedef __attribute__((ext_vector_type(8))) short short8;
typedef __attribute__((ext_vector_type(4))) float f32x4;
using bf16 = __hip_bfloat16;

#define T_SEQ 2048
#define NH 32
#define SCALE_F 0.07216878364870323f   // 192^-0.5

__device__ inline unsigned short f2bf(float f) {
    unsigned u = __builtin_bit_cast(unsigned, f);
    return (unsigned short)((u + 0x7fffu + ((u >> 16) & 1u)) >> 16);
}

__device__ inline void gload_lds16(const void* g, void* l) {
    __builtin_amdgcn_global_load_lds(
        (const __attribute__((address_space(1))) unsigned*)g,
        (__attribute__((address_space(3))) unsigned*)l, 16, 0, 0);
}

__device__ inline int sw4(int r) { return (r & 3) ^ ((r >> 2) & 3); }

// ---------------------------------------------------------------------------
// High-intensity GEMM: C[M,N] = A[M,K] * B^T. BM=256, BN=128, BK=32, 8 waves
// (4M x 2N, 64x64 each -> acc 4x4). 8 ds_read_b128 per 16 MFMA per K-step.
// Dbuf LDS 48KB (2 blocks/CU), counted vmcnt(3). 64B LDS rows -> 4-slot
// swizzle slot^=sw4(row%16) on both sides (pre-swizzled global src, rule #21).
// Requires M%256==0, N%128==0, K%32==0, lda/ldb %8==0.
// ---------------------------------------------------------------------------
template <typename TC>
__global__ __launch_bounds__(512, 4) void gemm256_kernel(
    const bf16* __restrict__ A, const bf16* __restrict__ B, TC* __restrict__ C,
    int K, int lda, int ldb, int ldc,
    long aStride, long bStride, long cStride)
{
    const int z = blockIdx.z;
    A += (long)z * aStride; B += (long)z * bStride; C += (long)z * cStride;
    const int bm = blockIdx.y * 256, bn = blockIdx.x * 128;
    __shared__ __align__(16) short As[2][256 * 32];
    __shared__ __align__(16) short Bs[2][128 * 32];
    const int tid = threadIdx.x, lane = tid & 63, w = tid >> 6;
    const int l15 = lane & 15, lg = lane >> 4;
    const int wm = w >> 1, wn = w & 1;
    // staging: lane covers chunk-row lr = lane>>2, slot = lane&3 (16B each).
    const int lr = lane >> 2;
    const int lcol = ((lane & 3) ^ sw4(lr)) * 8;     // pre-swizzled src elem
    const int arow0 = 32 * w + lr, arow1 = 32 * w + 16 + lr;
    const int brow = 16 * w + lr;
    const bf16* Ab = A + (long)bm * lda;
    const bf16* Bb = B + (long)bn * ldb;

    auto stage = [&](int buf, int k0) {
        gload_lds16(Ab + (long)arow0 * lda + k0 + lcol, &As[buf][(2 * w) * 512]);
        gload_lds16(Ab + (long)arow1 * lda + k0 + lcol, &As[buf][(2 * w + 1) * 512]);
        gload_lds16(Bb + (long)brow * ldb + k0 + lcol, &Bs[buf][w * 512]);
    };

    const int rs = sw4(l15);   // read-side slot XOR (row%16 == l15)
    f32x4 acc[4][4] = {};
    const int nt = K >> 5;
    stage(0, 0);
    for (int t = 0; t < nt; ++t) {
        if (t + 1 < nt) {
            stage((t + 1) & 1, (t + 1) << 5);
            asm volatile("s_waitcnt vmcnt(3)" ::: "memory");
        } else {
            asm volatile("s_waitcnt vmcnt(0)" ::: "memory");
        }
        __builtin_amdgcn_s_barrier();
        __builtin_amdgcn_sched_barrier(0);
        const char* Ap = (const char*)&As[t & 1][0];
        const char* Bp = (const char*)&Bs[t & 1][0];
        short8 af[4], bf[4];
        #pragma unroll
        for (int fi = 0; fi < 4; ++fi)
            af[fi] = *(const short8*)(Ap + (wm * 64 + fi * 16 + l15) * 64
                                      + ((lg ^ rs) << 4));
        #pragma unroll
        for (int nj = 0; nj < 4; ++nj)
            bf[nj] = *(const short8*)(Bp + (wn * 64 + nj * 16 + l15) * 64
                                      + ((lg ^ rs) << 4));
        #pragma unroll
        for (int fi = 0; fi < 4; ++fi)
            #pragma unroll
            for (int nj = 0; nj < 4; ++nj)
                acc[fi][nj] = __builtin_amdgcn_mfma_f32_16x16x32_bf16(
                    af[fi], bf[nj], acc[fi][nj], 0, 0, 0);
        asm volatile("s_waitcnt lgkmcnt(0)" ::: "memory");
        __builtin_amdgcn_sched_barrier(0);
        __builtin_amdgcn_s_barrier();
        __builtin_amdgcn_sched_barrier(0);
    }
    #pragma unroll
    for (int fi = 0; fi < 4; ++fi)
        #pragma unroll
        for (int nj = 0; nj < 4; ++nj)
            #pragma unroll
            for (int i = 0; i < 4; ++i) {
                const int row = bm + wm * 64 + fi * 16 + lg * 4 + i;
                const int col = bn + wn * 64 + nj * 16 + l15;
                if constexpr (std::is_same<TC, float>::value)
                    C[(long)row * ldc + col] = acc[fi][nj][i];
                else
                    ((unsigned short*)C)[(long)row * ldc + col] = f2bf(acc[fi][nj][i]);
            }
}

// ---------------------------------------------------------------------------
// Pipelined GEMM (round 6): BM=BN=128, BK=64, 8 waves, dbuf, vmcnt(4), T2 swz.
// ---------------------------------------------------------------------------
template <typename TC>
__global__ __launch_bounds__(512, 4) void gemm8w_kernel(
    const bf16* __restrict__ A, const bf16* __restrict__ B, TC* __restrict__ C,
    int K, int lda, int ldb, int ldc,
    long aStride, long bStride, long cStride)
{
    const int z = blockIdx.z;
    A += (long)z * aStride; B += (long)z * bStride; C += (long)z * cStride;
    const int bm = blockIdx.y * 128, bn = blockIdx.x * 128;
    __shared__ __align__(16) short As[2][128 * 64];
    __shared__ __align__(16) short Bs[2][128 * 64];
    const int tid = threadIdx.x, lane = tid & 63, w = tid >> 6;
    const int l15 = lane & 15, lg = lane >> 4;
    const int wm = w >> 1, wn = w & 1;
    const int c0 = w * 2, c1 = w * 2 + 1;
    const int srow0 = c0 * 8 + (lane >> 3), srow1 = c1 * 8 + (lane >> 3);
    const int scol = ((lane & 7) * 16) ^ ((lane >> 3) << 4);
    const bf16* Ab = A + (long)bm * lda;
    const bf16* Bb = B + (long)bn * ldb;

    auto stage = [&](int buf, int k0) {
        const char* ag = (const char*)(Ab + k0);
        const char* bg = (const char*)(Bb + k0);
        gload_lds16(ag + (long)srow0 * (lda * 2) + scol, &As[buf][c0 * 512]);
        gload_lds16(ag + (long)srow1 * (lda * 2) + scol, &As[buf][c1 * 512]);
        gload_lds16(bg + (long)srow0 * (ldb * 2) + scol, &Bs[buf][c0 * 512]);
        gload_lds16(bg + (long)srow1 * (ldb * 2) + scol, &Bs[buf][c1 * 512]);
    };

    const int swz = (l15 & 7) << 4;
    f32x4 acc[2][4] = {};
    const int nt = K >> 6;
    stage(0, 0);
    for (int t = 0; t < nt; ++t) {
        if (t + 1 < nt) {
            stage((t + 1) & 1, (t + 1) << 6);
            asm volatile("s_waitcnt vmcnt(4)" ::: "memory");
        } else {
            asm volatile("s_waitcnt vmcnt(0)" ::: "memory");
        }
        __builtin_amdgcn_s_barrier();
        __builtin_amdgcn_sched_barrier(0);
        const char* Ap = (const char*)&As[t & 1][0];
        const char* Bp = (const char*)&Bs[t & 1][0];
        short8 af[2][2], bfv[4][2];
        #pragma unroll
        for (int fi = 0; fi < 2; ++fi)
            #pragma unroll
            for (int ks = 0; ks < 2; ++ks)
                af[fi][ks] = *(const short8*)(Ap + (wm * 32 + fi * 16 + l15) * 128
                                              + ((ks * 64 + lg * 16) ^ swz));
        #pragma unroll
        for (int nj = 0; nj < 4; ++nj)
            #pragma unroll
            for (int ks = 0; ks < 2; ++ks)
                bfv[nj][ks] = *(const short8*)(Bp + (wn * 64 + nj * 16 + l15) * 128
                                               + ((ks * 64 + lg * 16) ^ swz));
        #pragma unroll
        for (int ks = 0; ks < 2; ++ks)
            #pragma unroll
            for (int fi = 0; fi < 2; ++fi)
                #pragma unroll
                for (int nj = 0; nj < 4; ++nj)
                    acc[fi][nj] = __builtin_amdgcn_mfma_f32_16x16x32_bf16(
                        af[fi][ks], bfv[nj][ks], acc[fi][nj], 0, 0, 0);
        asm volatile("s_waitcnt lgkmcnt(0)" ::: "memory");
        __builtin_amdgcn_sched_barrier(0);
        __builtin_amdgcn_s_barrier();
        __builtin_amdgcn_sched_barrier(0);
    }
    #pragma unroll
    for (int fi = 0; fi < 2; ++fi)
        #pragma unroll
        for (int nj = 0; nj < 4; ++nj)
            #pragma unroll
            for (int i = 0; i < 4; ++i) {
                const int row = bm + wm * 32 + fi * 16 + lg * 4 + i;
                const int col = bn + wn * 64 + nj * 16 + l15;
                if constexpr (std::is_same<TC, float>::value)
                    C[(long)row * ldc + col] = acc[fi][nj][i];
                else
                    ((unsigned short*)C)[(long)row * ldc + col] = f2bf(acc[fi][nj][i]);
            }
}

// ---------------------------------------------------------------------------
__global__ __launch_bounds__(256) void cvt_kernel(
    const float* __restrict__ in, bf16* __restrict__ out, long n, float scale)
{
    const long i = ((long)blockIdx.x * 256 + threadIdx.x) * 8;
    if (i >= n) return;
    f32x4 a = *(const f32x4*)(in + i), b = *(const f32x4*)(in + i + 4);
    short8 r;
    r[0] = (short)f2bf(a[0] * scale); r[1] = (short)f2bf(a[1] * scale);
    r[2] = (short)f2bf(a[2] * scale); r[3] = (short)f2bf(a[3] * scale);
    r[4] = (short)f2bf(b[0] * scale); r[5] = (short)f2bf(b[1] * scale);
    r[6] = (short)f2bf(b[2] * scale); r[7] = (short)f2bf(b[3] * scale);
    *(short8*)(out + i) = r;
}

// ---------------------------------------------------------------------------
__global__ __launch_bounds__(256) void tconv_kernel(
    const float* __restrict__ in, bf16* __restrict__ out)
{
    const int h = blockIdx.z, k0 = blockIdx.x * 32, d0 = blockIdx.y * 32;
    __shared__ float t[32][33];
    const int r = threadIdx.x >> 5, c = threadIdx.x & 31;
    const float* ip = in + ((long)h * 512 + k0) * 128 + d0;
    #pragma unroll
    for (int it = 0; it < 4; ++it)
        t[r + 8 * it][c] = ip[(long)(r + 8 * it) * 128 + c];
    __syncthreads();
    bf16* op = out + ((long)h * 128 + d0) * 512 + k0;
    #pragma unroll
    for (int it = 0; it < 4; ++it)
        op[(long)(r + 8 * it) * 512 + c] = __float2bfloat16(t[c][r + 8 * it]);
}

// ---------------------------------------------------------------------------
__global__ __launch_bounds__(256) void rmsnorm_kernel(
    bf16* __restrict__ x, const float* __restrict__ w, int C, int ld)
{
    bf16* row = x + (long)blockIdx.x * ld;
    float ss = 0.f;
    for (int i = threadIdx.x; i < C; i += 256) {
        float v = __bfloat162float(row[i]);
        ss += v * v;
    }
    #pragma unroll
    for (int m = 1; m < 64; m <<= 1) ss += __shfl_xor(ss, m, 64);
    __shared__ float red[4];
    if ((threadIdx.x & 63) == 0) red[threadIdx.x >> 6] = ss;
    __syncthreads();
    ss = red[0] + red[1] + red[2] + red[3];
    float scale = rsqrtf(ss / (float)C + 1e-6f);
    for (int i = threadIdx.x; i < C; i += 256) {
        float v = __bfloat162float(row[i]);
        row[i] = __float2bfloat16(v * scale * w[i]);
    }
}

// ---------------------------------------------------------------------------
__global__ __launch_bounds__(256) void ropeq_kernel(bf16* __restrict__ q)
{
    const int t = blockIdx.x;
    #pragma unroll
    for (int it = 0; it < 4; ++it) {
        const int pair = threadIdx.x + 256 * it;
        const int h = pair >> 5, i = pair & 31;
        bf16* base = q + ((long)t * NH + h) * 192;
        float x1 = __bfloat162float(base[128 + i]);
        float x2 = __bfloat162float(base[160 + i]);
        float inv = powf(10000.f, -(float)i / 32.f);
        float ang = (float)t * inv, s, c;
        sincosf(ang, &s, &c);
        base[128 + i] = __float2bfloat16(x1 * c - x2 * s);
        base[160 + i] = __float2bfloat16(x2 * c + x1 * s);
    }
}

// ---------------------------------------------------------------------------
__global__ __launch_bounds__(1024) void ropek_kernel(
    const bf16* __restrict__ ckv, bf16* __restrict__ kf, int ld)
{
    const int t = blockIdx.x;
    const int h = threadIdx.x >> 5, i = threadIdx.x & 31;
    float x1 = __bfloat162float(ckv[(long)t * ld + 512 + i]);
    float x2 = __bfloat162float(ckv[(long)t * ld + 544 + i]);
    float inv = powf(10000.f, -(float)i / 32.f);
    float ang = (float)t * inv, s, c;
    sincosf(ang, &s, &c);
    bf16* kb = kf + ((long)h * T_SEQ + t) * 192;
    kb[128 + i] = __float2bfloat16(x1 * c - x2 * s);
    kb[160 + i] = __float2bfloat16(x2 * c + x1 * s);
}

// ---------------------------------------------------------------------------
// Flash attention (round-6 body: gload_lds staging, __syncthreads barriers)
// with round-7 1-D XCD-grouped, causally-paired grid.
// ---------------------------------------------------------------------------
__global__ __launch_bounds__(256, 2) void attn_kernel(
    const bf16* __restrict__ Q,   // [T][H][192] scaled+roped
    const bf16* __restrict__ Kf,  // [H][T][192]
    const bf16* __restrict__ Vt,  // [H][128][T]  (V^T)
    bf16* __restrict__ O)         // [T][H*128]
{
    const int lin = blockIdx.x;
    const int h = (lin & 7) + 8 * ((lin >> 3) & 3);
    const int qraw = lin >> 5;
    const int qblk = (qraw < 8) ? (2 * qraw) : (31 - 2 * qraw);
    const int q0 = qblk * 128;
    const int tid = threadIdx.x, lane = tid & 63, w = tid >> 6;
    const int l15 = lane & 15, lg = lane >> 4;
    const int qw = q0 + w * 32;
    __shared__ __align__(16) short Ks[64 * 192];
    __shared__ __align__(16) short Vs[128 * 64];

    int ksoff[6];
    #pragma unroll
    for (int j = 0; j < 6; ++j) {
        int o = (w * 6 + j) * 1024 + lane * 16;
        int row = o / 384, col = o % 384;
        ksoff[j] = row * 384 + (col ^ ((row & 7) << 4));
    }
    const int vrow8 = lane >> 3;
    const int vscol = ((lane & 7) * 16) ^ (vrow8 << 4);

    short8 qf[2][6];
    #pragma unroll
    for (int qi = 0; qi < 2; ++qi) {
        const bf16* qp = Q + (long)(qw + qi * 16 + l15) * (NH * 192) + (long)h * 192;
        #pragma unroll
        for (int c = 0; c < 6; ++c) qf[qi][c] = *(const short8*)(qp + c * 32 + lg * 8);
    }

    f32x4 oacc[2][8] = {};
    float mst[2] = {-INFINITY, -INFINITY};
    float lst[2] = {0.f, 0.f};

    const char* kbase0 = (const char*)Kf + (long)h * T_SEQ * 384;
    const char* vbase0 = (const char*)Vt + (long)h * 128 * (T_SEQ * 2);
    const int swz = (l15 & 7) << 4;

    for (int s0 = 0; s0 < q0 + 128; s0 += 64) {
        {
            const char* kb = kbase0 + (long)s0 * 384;
            #pragma unroll
            for (int j = 0; j < 6; ++j)
                gload_lds16(kb + ksoff[j], (char*)Ks + (w * 6 + j) * 1024);
            const char* vb = vbase0 + (long)s0 * 2 + vscol;
            #pragma unroll
            for (int j = 0; j < 4; ++j) {
                const int c = w * 4 + j;
                gload_lds16(vb + (long)(c * 8 + vrow8) * (T_SEQ * 2),
                            (char*)Vs + c * 1024);
            }
        }
        __syncthreads();
        if (s0 <= qw + 31) {
            f32x4 st[2][4] = {};
            __builtin_amdgcn_s_setprio(1);
            #pragma unroll
            for (int cb = 0; cb < 4; ++cb) {
                const int krow = cb * 16 + l15;
                #pragma unroll
                for (int c = 0; c < 6; ++c) {
                    short8 kfr = *(const short8*)((const char*)Ks + krow * 384
                                                  + ((c * 64 + lg * 16) ^ swz));
                    st[0][cb] = __builtin_amdgcn_mfma_f32_16x16x32_bf16(kfr, qf[0][c], st[0][cb], 0, 0, 0);
                    st[1][cb] = __builtin_amdgcn_mfma_f32_16x16x32_bf16(kfr, qf[1][c], st[1][cb], 0, 0, 0);
                }
            }
            __builtin_amdgcn_s_setprio(0);
            short8 pb[2][2];
            #pragma unroll
            for (int qi = 0; qi < 2; ++qi) {
                const int qg = qw + qi * 16 + l15;
                float pmax = -INFINITY;
                #pragma unroll
                for (int cb = 0; cb < 4; ++cb)
                    #pragma unroll
                    for (int i = 0; i < 4; ++i) {
                        const int kv = s0 + cb * 16 + lg * 4 + i;
                        float v = (kv <= qg) ? st[qi][cb][i] : -INFINITY;
                        st[qi][cb][i] = v;
                        pmax = fmaxf(pmax, v);
                    }
                pmax = fmaxf(pmax, __shfl_xor(pmax, 16, 64));
                pmax = fmaxf(pmax, __shfl_xor(pmax, 32, 64));
                const float newm = fmaxf(mst[qi], pmax);
                const float mm = (newm == -INFINITY) ? 0.f : newm;
                const float alpha = __expf(mst[qi] - mm);
                float ps = 0.f;
                #pragma unroll
                for (int cb = 0; cb < 4; ++cb)
                    #pragma unroll
                    for (int i = 0; i < 4; ++i) {
                        const float e = __expf(st[qi][cb][i] - mm);
                        st[qi][cb][i] = e; ps += e;
                    }
                ps += __shfl_xor(ps, 16, 64);
                ps += __shfl_xor(ps, 32, 64);
                lst[qi] = lst[qi] * alpha + ps;
                mst[qi] = newm;
                #pragma unroll
                for (int mb = 0; mb < 8; ++mb) oacc[qi][mb] *= alpha;
                #pragma unroll
                for (int hh = 0; hh < 2; ++hh) {
                    unsigned pk[4];
                    #pragma unroll
                    for (int i = 0; i < 4; ++i)
                        pk[i] = (unsigned)f2bf(st[qi][2 * hh][i])
                              | ((unsigned)f2bf(st[qi][2 * hh + 1][i]) << 16);
                    #pragma unroll
                    for (int j = 0; j < 8; ++j) {
                        const int src = l15 + (((2 * lg + (j >> 2)) & 3) << 4);
                        const unsigned u = (unsigned)__shfl((int)pk[j & 3], src, 64);
                        pb[qi][hh][j] = (short)((lg >> 1) ? (u >> 16) : (u & 0xffffu));
                    }
                }
            }
            __builtin_amdgcn_s_setprio(1);
            #pragma unroll
            for (int mb = 0; mb < 8; ++mb) {
                const int vrow = mb * 16 + l15;
                #pragma unroll
                for (int hh = 0; hh < 2; ++hh) {
                    short8 vfr = *(const short8*)((const char*)Vs + vrow * 128
                                                  + ((hh * 64 + lg * 16) ^ swz));
                    oacc[0][mb] = __builtin_amdgcn_mfma_f32_16x16x32_bf16(vfr, pb[0][hh], oacc[0][mb], 0, 0, 0);
                    oacc[1][mb] = __builtin_amdgcn_mfma_f32_16x16x32_bf16(vfr, pb[1][hh], oacc[1][mb], 0, 0, 0);
                }
            }
            __builtin_amdgcn_s_setprio(0);
        }
        __syncthreads();
    }
    #pragma unroll
    for (int qi = 0; qi < 2; ++qi) {
        const float inv = 1.f / lst[qi];
        const int qg = qw + qi * 16 + l15;
        #pragma unroll
        for (int mb = 0; mb < 8; ++mb)
            #pragma unroll
            for (int i = 0; i < 4; ++i) {
                const int dv = mb * 16 + lg * 4 + i;
                O[(long)qg * (NH * 128) + h * 128 + dv] = __float2bfloat16(oacc[qi][mb][i] * inv);
            }
    }
}

// ---------------------------------------------------------------------------
extern "C" void kernel_launch(void* const* d_in, const int* in_sizes, int n_in,
                              void* d_out, int out_size, void* d_ws, size_t ws_size,
                              hipStream_t stream)
{
    const float* hidden    = (const float*)d_in[0];
    const float* w_q_a     = (const float*)d_in[2];
    const float* q_a_ln_w  = (const float*)d_in[3];
    const float* w_q_b     = (const float*)d_in[4];
    const float* w_kv_a    = (const float*)d_in[5];
    const float* kv_a_ln_w = (const float*)d_in[6];
    const float* w_kc      = (const float*)d_in[7];
    const float* w_vc      = (const float*)d_in[8];
    const float* w_o       = (const float*)d_in[9];
    float* out = (float*)d_out;

    // workspace layout (bf16 elements)
    bf16* qckv  = (bf16*)d_ws;                      // [2048][2176]: qa | ckv(640)
    bf16* qbuf  = qckv  + (long)T_SEQ * 2176;       // [2048][32][192]
    bf16* kf    = qbuf  + (long)T_SEQ * 6144;       // [32][2048][192]
    bf16* vt    = kf    + (long)NH * T_SEQ * 192;   // [32][128][2048]  (V^T)
    bf16* ov    = vt    + (long)NH * 128 * T_SEQ;   // [2048][4096]
    bf16* hb    = ov    + (long)T_SEQ * 4096;       // [2048][5120] hidden bf16
    bf16* wqckv = hb    + (long)T_SEQ * 5120;       // [2176][5120]: w_q_a|w_kv_a|pad
    bf16* wqb   = wqckv + (long)2176 * 5120;        // [6144][1536]
    bf16* wkc   = wqb   + (long)6144 * 1536;        // [32][128][512]
    bf16* wvct  = wkc   + (long)NH * 128 * 512;     // [32][128][512]  (w_vc^T)
    bf16* wo    = hb;   // alias: hb/wqckv/wqb region dead by then
    bf16* ckv   = qckv + 1536;                      // ckv rows, stride 2176

    // --- conversions ---
    cvt_kernel<<<dim3(5120), 256, 0, stream>>>(hidden, hb, (long)T_SEQ * 5120, 1.f);
    cvt_kernel<<<dim3(3840), 256, 0, stream>>>(w_q_a, wqckv, (long)1536 * 5120, 1.f);
    cvt_kernel<<<dim3(1440), 256, 0, stream>>>(w_kv_a, wqckv + (long)1536 * 5120,
                                               (long)576 * 5120, 1.f);
    hipMemsetAsync(wqckv + (long)2112 * 5120, 0, (long)64 * 5120 * sizeof(bf16), stream);
    cvt_kernel<<<dim3(4608), 256, 0, stream>>>(w_q_b, wqb, (long)6144 * 1536, SCALE_F);
    cvt_kernel<<<dim3(1024), 256, 0, stream>>>(w_kc, wkc, (long)NH * 128 * 512, 1.f);
    tconv_kernel<<<dim3(16, 4, NH), 256, 0, stream>>>(w_vc, wvct);

    // 1+5 merged: qckv = hb @ wqckv^T   (M=2048, N=2176, K=5120)
    gemm8w_kernel<bf16><<<dim3(17, 16, 1), 512, 0, stream>>>(
        hb, wqckv, qckv, 5120, 5120, 5120, 2176, 0, 0, 0);
    // 2. rmsnorm(qa)
    rmsnorm_kernel<<<dim3(T_SEQ), 256, 0, stream>>>(qckv, q_a_ln_w, 1536, 2176);
    // 6. rmsnorm(ckv[:, :512])
    rmsnorm_kernel<<<dim3(T_SEQ), 256, 0, stream>>>(ckv, kv_a_ln_w, 512, 2176);
    // 3. q = qa @ wqb^T   (M=2048, N=6144, K=1536) — high-intensity kernel
    gemm256_kernel<bf16><<<dim3(48, 8, 1), 512, 0, stream>>>(
        qckv, wqb, qbuf, 1536, 2176, 1536, 6144, 0, 0, 0);
    // 4. rope q
    ropeq_kernel<<<dim3(T_SEQ), 256, 0, stream>>>(qbuf);
    // 7. rope k_pe -> kf[:,:,128:192]
    ropek_kernel<<<dim3(T_SEQ), 1024, 0, stream>>>(ckv, kf, 2176);
    // 8. k_nope[h] = ckv_n @ wkc[h]^T   (batched, M=2048, N=128, K=512)
    gemm256_kernel<bf16><<<dim3(1, 8, NH), 512, 0, stream>>>(
        ckv, wkc, kf, 512, 2176, 512, 192,
        0, (long)128 * 512, (long)T_SEQ * 192);
    // 9. vt[h] = wvct[h] @ ckv_n^T      (batched, M=128, N=2048, K=512)
    gemm8w_kernel<bf16><<<dim3(16, 1, NH), 512, 0, stream>>>(
        wvct, ckv, vt, 512, 512, 2176, T_SEQ,
        (long)128 * 512, 0, (long)128 * T_SEQ);
    // 10. convert w_o
    cvt_kernel<<<dim3(10240), 256, 0, stream>>>(w_o, wo, (long)5120 * 4096, 1.f);
    // 11. attention
    attn_kernel<<<dim3(512), 256, 0, stream>>>(qbuf, kf, vt, ov);
    // 12. out = ov @ wo^T   (M=2048, N=5120, K=4096), fp32 out
    gemm256_kernel<float><<<dim3(40, 8, 1), 512, 0, stream>>>(
        ov, wo, out, 4096, 4096, 4096, 5120, 0, 0, 0);
}